// Round 1
// baseline (665.866 us; speedup 1.0000x reference)
//
#include <hip/hip_runtime.h>
#include <hip/hip_bf16.h>

// Problem constants: B=1, N=3, C=128, H=W=256, HEADS=4, hd=32, SCALES=[16,8,4]

typedef __attribute__((ext_vector_type(8))) short bf16x8;
typedef __attribute__((ext_vector_type(4))) float f32x4;

__device__ inline ushort rne_bf16(float x) {
  uint u = __float_as_uint(x);
  return (ushort)((u + 0x7fffu + ((u >> 16) & 1u)) >> 16);
}

__device__ inline uint pk2_bf16(float a, float b) {
  float2 f2; f2.x = a; f2.y = b;
  __hip_bfloat162 h = __float22bfloat162_rn(f2);   // v_cvt_pk_bf16_f32
  union { __hip_bfloat162 h; uint u; } cvt; cvt.h = h;
  return cvt.u;
}

// ---------------- pool by 4: query/keys/values -> pooled4 [7][128][64][64]
__global__ __launch_bounds__(256) void pool4_kernel(
    const float* __restrict__ query, const float* __restrict__ keys,
    const float* __restrict__ values, float* __restrict__ out)
{
  int idx = blockIdx.x * 256 + threadIdx.x;      // [0, 7*128*4096)
  int x = idx & 63, y = (idx >> 6) & 63, mc = idx >> 12;   // mc = map*128 + c
  int map = mc >> 7, c = mc & 127;
  const float* src;
  if (map == 0)      src = query  + (size_t)c * 65536;
  else if (map <= 3) src = keys   + (size_t)((map - 1) * 128 + c) * 65536;
  else               src = values + (size_t)((map - 4) * 128 + c) * 65536;
  src += (y * 4) * 256 + x * 4;
  float s = 0.f;
#pragma unroll
  for (int r = 0; r < 4; ++r) {
    float4 v = *(const float4*)(src + r * 256);
    s += v.x + v.y + v.z + v.w;
  }
  out[idx] = s * 0.0625f;
}

// ---------------- pool by 2 (generic): [896][2w][2w] -> [896][w][w]
__global__ __launch_bounds__(256) void pool2_kernel(
    const float* __restrict__ in, float* __restrict__ out, int hw)
{
  int idx = blockIdx.x * 256 + threadIdx.x;
  int x = idx % hw; int y = (idx / hw) % hw; int mc = idx / (hw * hw);
  int w2 = hw * 2;
  const float* s = in + (size_t)mc * w2 * w2 + (2 * y) * w2 + 2 * x;
  float2 a = *(const float2*)s;
  float2 b = *(const float2*)(s + w2);
  out[idx] = (a.x + a.y + b.x + b.y) * 0.25f;
}

// ---------------- precompute Wc = out_w @ fusion_w  [128][384], bc = out_b + out_w @ fusion_b
__global__ __launch_bounds__(256) void precomp_kernel(
    const float* __restrict__ fusion_w, const float* __restrict__ fusion_b,
    const float* __restrict__ out_w, const float* __restrict__ out_b,
    float* __restrict__ Wc, float* __restrict__ bc)
{
  int idx = blockIdx.x * 256 + threadIdx.x;
  if (idx < 128 * 384) {
    int o = idx / 384, k = idx % 384;
    float s = 0.f;
    for (int c = 0; c < 128; ++c)
      s = fmaf(out_w[o * 128 + c], fusion_w[c * 384 + k], s);
    Wc[idx] = s;
  } else if (idx < 128 * 384 + 128) {
    int o = idx - 128 * 384;
    float s = out_b[o];
    for (int c = 0; c < 128; ++c)
      s = fmaf(out_w[o * 128 + c], fusion_b[c], s);
    bc[o] = s;
  }
}

// ---------------- 1x1 conv projection -> bf16 operand arrays in MFMA layouts
// map 0: qb[head][L][32] (scaled);  maps 1-3: kb[a][head][L][32]
// maps 4-6: vb[a][head] in MFMA-frag chunks: chunk=(m>>5)*2+(d>>4), 512 elems:
//           [d&15][ (m>>3)&3 ][ m&7 ]  -> attn reads 1 KB fully coalesced
__global__ __launch_bounds__(256) void proj_kernel(
    const float* __restrict__ pooled,
    ushort* __restrict__ qb, ushort* __restrict__ kbb, ushort* __restrict__ vbb,
    const float* __restrict__ wq, const float* __restrict__ bq,
    const float* __restrict__ wk, const float* __restrict__ bk,
    const float* __restrict__ wv, const float* __restrict__ bv,
    int si, int L, float qscale)
{
  __shared__ float Wt[32][68];
  __shared__ float Xs[32][64];
  int map = blockIdx.z;
  int o0 = blockIdx.y * 64;
  int l0 = blockIdx.x * 64;
  const float* w; const float* b; float sc = 1.f;
  if (map == 0)      { w = wq + si * 16384; b = bq + si * 128; sc = qscale; }
  else if (map <= 3) { w = wk + si * 16384; b = bk + si * 128; }
  else               { w = wv + si * 16384; b = bv + si * 128; }
  const float* src = pooled + (size_t)map * 128 * L;
  int t = threadIdx.x;
  int og = t >> 4, lg = t & 15;
  float acc[4][4] = {};
  for (int c0 = 0; c0 < 128; c0 += 32) {
    __syncthreads();
    { // stage W[64 o][32 c] -> Wt[c][o]
      int o = t >> 2, ci = (t & 3) * 8;
      const float* wp = w + (o0 + o) * 128 + c0 + ci;
      float4 a = *(const float4*)wp, d = *(const float4*)(wp + 4);
      Wt[ci + 0][o] = a.x; Wt[ci + 1][o] = a.y; Wt[ci + 2][o] = a.z; Wt[ci + 3][o] = a.w;
      Wt[ci + 4][o] = d.x; Wt[ci + 5][o] = d.y; Wt[ci + 6][o] = d.z; Wt[ci + 7][o] = d.w;
    }
    { // stage X[32 c][64 l]
      int c = t >> 3, li = (t & 7) * 8;
      const float* xp = src + (size_t)(c0 + c) * L + l0 + li;
      float4 a = *(const float4*)xp, d = *(const float4*)(xp + 4);
      *(float4*)&Xs[c][li] = a; *(float4*)&Xs[c][li + 4] = d;
    }
    __syncthreads();
#pragma unroll 8
    for (int k = 0; k < 32; ++k) {
      float4 wv4 = *(const float4*)&Wt[k][4 * og];
      float4 xv4 = *(const float4*)&Xs[k][4 * lg];
      float wa[4] = {wv4.x, wv4.y, wv4.z, wv4.w};
      float xa[4] = {xv4.x, xv4.y, xv4.z, xv4.w};
#pragma unroll
      for (int r = 0; r < 4; ++r)
#pragma unroll
        for (int c = 0; c < 4; ++c)
          acc[r][c] = fmaf(wa[r], xa[c], acc[r][c]);
    }
  }
  float4 b4 = *(const float4*)&b[o0 + 4 * og];
  float ba[4] = {b4.x, b4.y, b4.z, b4.w};
  if (map < 4) {
    ushort* dst = (map == 0) ? qb : (kbb + (size_t)(map - 1) * L * 32 * 4);
    int o4 = o0 + 4 * og;
    size_t hbase = (size_t)(o4 >> 5) * L * 32 + (o4 & 31);
#pragma unroll
    for (int li = 0; li < 4; ++li) {
      ushort4 r;
      r.x = rne_bf16((acc[0][li] + ba[0]) * sc);
      r.y = rne_bf16((acc[1][li] + ba[1]) * sc);
      r.z = rne_bf16((acc[2][li] + ba[2]) * sc);
      r.w = rne_bf16((acc[3][li] + ba[3]) * sc);
      *(ushort4*)&dst[hbase + (size_t)(l0 + 4 * lg + li) * 32] = r;
    }
  } else {
    ushort* dst = vbb + (size_t)(map - 4) * 128 * L;   // per-anchor 4 heads * 32*L
    int m = l0 + 4 * lg;                               // 4-aligned
#pragma unroll
    for (int oi = 0; oi < 4; ++oi) {
      int o = o0 + 4 * og + oi;            // c = h*32 + d
      int h = o >> 5, d = o & 31;
      ushort4 r;
      r.x = rne_bf16(acc[oi][0] + ba[oi]);
      r.y = rne_bf16(acc[oi][1] + ba[oi]);
      r.z = rne_bf16(acc[oi][2] + ba[oi]);
      r.w = rne_bf16(acc[oi][3] + ba[oi]);
      size_t off = (size_t)h * 32 * L
                 + ((size_t)(m >> 5) * 2 + (d >> 4)) * 512
                 + (size_t)(d & 15) * 32 + ((m >> 3) & 3) * 8 + (m & 7);
      *(ushort4*)&dst[off] = r;
    }
  }
}

// ---------------- MFMA flash attention, S^T form, P double-buffered in LDS.
// Iteration i: S_i = K_i Q^T (MFMA), exp2+pack -> P buf[i&1], while PV/row-sum
// consume P_{i-1} from buf[(i-1)&1] (LDS write->read distance = 1 iteration).
// Row-sums of the ROUNDED P via MFMA against all-ones B (exact: P*1.0 in f32).
// Q is pre-scaled by log2(e)/sqrt(hd) in proj -> exp2 directly (no mul).
// Accumulates UNNORMALIZED O into onum[a][c][L] and row-sums into lsum[a][h][L].
#define PSTR 72
__global__ __launch_bounds__(256, 4) void attn_mfma_kernel(
    const ushort* __restrict__ qb, const ushort* __restrict__ kb,
    const ushort* __restrict__ vb, float* __restrict__ onum,
    float* __restrict__ lsum, int L, int msplit)
{
  __shared__ __align__(16) ushort P[2][4][16][PSTR];   // 18432 B
  int t = threadIdx.x;
  int wave = t >> 6, lane = t & 63;
  int col = lane & 15, quad = lane >> 4;
  int head = blockIdx.y;
  int anchor = blockIdx.z / msplit, mpart = blockIdx.z % msplit;
  int l = blockIdx.x * 64 + wave * 16;
  int mlen = L / msplit, mbase = mpart * mlen;
  int ntile = mlen >> 6;

  const ushort* qh = qb + (size_t)head * L * 32;
  const ushort* kh = kb + ((size_t)anchor * 4 + head) * L * 32;
  const ushort* vh = vb + ((size_t)anchor * 4 + head) * 32 * L;

  bf16x8 qf = *(const bf16x8*)(qh + (size_t)(l + col) * 32 + quad * 8);
  const ushort* kbase = kh + (size_t)mbase * 32 + col * 32 + quad * 8;
  const ushort* vbase = vh + (size_t)(mbase >> 5) * 1024 + col * 32 + quad * 8;

  f32x4 od0 = {0.f,0.f,0.f,0.f};   // O[l-local][d 0..16)
  f32x4 od1 = {0.f,0.f,0.f,0.f};   // O[l-local][d 16..32)
  f32x4 lsa = {0.f,0.f,0.f,0.f};   // row-sums of rounded P, rows l-local
  const f32x4 z = {0.f,0.f,0.f,0.f};
  const bf16x8 ones = {16256,16256,16256,16256,16256,16256,16256,16256}; // bf16 1.0

  ushort* Pa = &P[0][wave][0][0];
  ushort* Pb = &P[1][wave][0][0];

  auto expstore = [&](f32x4 a0, f32x4 a1, f32x4 a2, f32x4 a3, ushort* Pw) {
    float sv[4][4] = {{a0.x,a0.y,a0.z,a0.w},{a1.x,a1.y,a1.z,a1.w},
                      {a2.x,a2.y,a2.z,a2.w},{a3.x,a3.y,a3.z,a3.w}};
#pragma unroll
    for (int j = 0; j < 4; ++j) {
      uint u0 = pk2_bf16(__builtin_amdgcn_exp2f(sv[j][0]),
                         __builtin_amdgcn_exp2f(sv[j][1]));
      uint u1 = pk2_bf16(__builtin_amdgcn_exp2f(sv[j][2]),
                         __builtin_amdgcn_exp2f(sv[j][3]));
      uint2 dw; dw.x = u0; dw.y = u1;
      *(uint2*)&Pw[col * PSTR + 16 * j + quad * 4] = dw;
    }
  };

  // ---- prologue: scores for tile 0, prefetch K tile 1
  bf16x8 k0 = *(const bf16x8*)(kbase);
  bf16x8 k1 = *(const bf16x8*)(kbase + 512);
  bf16x8 k2 = *(const bf16x8*)(kbase + 1024);
  bf16x8 k3 = *(const bf16x8*)(kbase + 1536);
  f32x4 s0 = __builtin_amdgcn_mfma_f32_16x16x32_bf16(k0, qf, z, 0, 0, 0);
  f32x4 s1 = __builtin_amdgcn_mfma_f32_16x16x32_bf16(k1, qf, z, 0, 0, 0);
  f32x4 s2 = __builtin_amdgcn_mfma_f32_16x16x32_bf16(k2, qf, z, 0, 0, 0);
  f32x4 s3 = __builtin_amdgcn_mfma_f32_16x16x32_bf16(k3, qf, z, 0, 0, 0);
  {
    const ushort* kp1 = kbase + ((ntile > 1) ? 64 * 32 : 0);
    k0 = *(const bf16x8*)(kp1);
    k1 = *(const bf16x8*)(kp1 + 512);
    k2 = *(const bf16x8*)(kp1 + 1024);
    k3 = *(const bf16x8*)(kp1 + 1536);
  }
  expstore(s0, s1, s2, s3, Pa);

  for (int i = 1; i < ntile; ++i) {
    // K tile i+1 (dummy reload of tile 0 on last iteration)
    const ushort* kpn = kbase + ((i + 1 < ntile) ? (i + 1) * 2048 : 0);
    bf16x8 n0 = *(const bf16x8*)(kpn);
    bf16x8 n1 = *(const bf16x8*)(kpn + 512);
    bf16x8 n2 = *(const bf16x8*)(kpn + 1024);
    bf16x8 n3 = *(const bf16x8*)(kpn + 1536);
    // V tile i-1 (consumed below, after ~p-read + S-MFMA cover)
    const ushort* vpn = vbase + (i - 1) * 2048;
    bf16x8 vA = *(const bf16x8*)(vpn);            // d 0..15,  m-chunk 0
    bf16x8 vB = *(const bf16x8*)(vpn + 1024);     // d 0..15,  m-chunk 1
    bf16x8 vC = *(const bf16x8*)(vpn + 512);      // d 16..31, m-chunk 0
    bf16x8 vD = *(const bf16x8*)(vpn + 1536);     // d 16..31, m-chunk 1
    // P tile i-1 from LDS (written one iteration ago -> wait is free)
    bf16x8 p0 = *(const bf16x8*)(&Pa[col * PSTR + quad * 8]);
    bf16x8 p1 = *(const bf16x8*)(&Pa[col * PSTR + 32 + quad * 8]);
    // scores for tile i
    f32x4 t0 = __builtin_amdgcn_mfma_f32_16x16x32_bf16(k0, qf, z, 0, 0, 0);
    f32x4 t1 = __builtin_amdgcn_mfma_f32_16x16x32_bf16(k1, qf, z, 0, 0, 0);
    f32x4 t2 = __builtin_amdgcn_mfma_f32_16x16x32_bf16(k2, qf, z, 0, 0, 0);
    f32x4 t3 = __builtin_amdgcn_mfma_f32_16x16x32_bf16(k3, qf, z, 0, 0, 0);
    // row-sums of rounded P (exact) + PV for tile i-1
    lsa = __builtin_amdgcn_mfma_f32_16x16x32_bf16(p0, ones, lsa, 0, 0, 0);
    lsa = __builtin_amdgcn_mfma_f32_16x16x32_bf16(p1, ones, lsa, 0, 0, 0);
    od0 = __builtin_amdgcn_mfma_f32_16x16x32_bf16(p0, vA, od0, 0, 0, 0);
    od0 = __builtin_amdgcn_mfma_f32_16x16x32_bf16(p1, vB, od0, 0, 0, 0);
    od1 = __builtin_amdgcn_mfma_f32_16x16x32_bf16(p0, vC, od1, 0, 0, 0);
    od1 = __builtin_amdgcn_mfma_f32_16x16x32_bf16(p1, vD, od1, 0, 0, 0);
    // exp2 + RNE pack tile i -> other buffer
    expstore(t0, t1, t2, t3, Pb);
    k0 = n0; k1 = n1; k2 = n2; k3 = n3;
    ushort* tp = Pa; Pa = Pb; Pb = tp;
  }

  // ---- epilogue: PV + row-sum for last tile
  {
    const ushort* vpe = vbase + (ntile - 1) * 2048;
    bf16x8 vA = *(const bf16x8*)(vpe);
    bf16x8 vB = *(const bf16x8*)(vpe + 1024);
    bf16x8 vC = *(const bf16x8*)(vpe + 512);
    bf16x8 vD = *(const bf16x8*)(vpe + 1536);
    bf16x8 p0 = *(const bf16x8*)(&Pa[col * PSTR + quad * 8]);
    bf16x8 p1 = *(const bf16x8*)(&Pa[col * PSTR + 32 + quad * 8]);
    lsa = __builtin_amdgcn_mfma_f32_16x16x32_bf16(p0, ones, lsa, 0, 0, 0);
    lsa = __builtin_amdgcn_mfma_f32_16x16x32_bf16(p1, ones, lsa, 0, 0, 0);
    od0 = __builtin_amdgcn_mfma_f32_16x16x32_bf16(p0, vA, od0, 0, 0, 0);
    od0 = __builtin_amdgcn_mfma_f32_16x16x32_bf16(p1, vB, od0, 0, 0, 0);
    od1 = __builtin_amdgcn_mfma_f32_16x16x32_bf16(p0, vC, od1, 0, 0, 0);
    od1 = __builtin_amdgcn_mfma_f32_16x16x32_bf16(p1, vD, od1, 0, 0, 0);
  }

  // lsa D-layout: row l-local = quad*4+r (all 16 cols identical copies)
  float* lsp = lsum + ((size_t)anchor * 4 + head) * L;
  if (col == 0) {
#pragma unroll
    for (int r = 0; r < 4; ++r)
      atomicAdd(&lsp[l + quad * 4 + r], lsa[r]);
  }
  float* on = onum + (size_t)anchor * 128 * L + (size_t)(head * 32) * L;
#pragma unroll
  for (int r = 0; r < 4; ++r) {
    atomicAdd(&on[(size_t)col * L + l + quad * 4 + r],        od0[r]);
    atomicAdd(&on[(size_t)(16 + col) * L + l + quad * 4 + r], od1[r]);
  }
}

// ---------------- normalize: A[c][l] = (1/3) * sum_a onum[a][c][l] / lsum[a][h][l]
__global__ __launch_bounds__(256) void norm_kernel(
    const float* __restrict__ on4,  const float* __restrict__ ls4,  float* __restrict__ a4,
    const float* __restrict__ on8,  const float* __restrict__ ls8,  float* __restrict__ a8,
    const float* __restrict__ on16, const float* __restrict__ ls16, float* __restrict__ a16)
{
  int i = blockIdx.x * 256 + threadIdx.x;   // float4 index
  const float* on; const float* ls; float* ax; int L;
  if (i < 131072)      { on = on4;  ls = ls4;  ax = a4;  L = 4096; }
  else if (i < 163840) { i -= 131072; on = on8;  ls = ls8;  ax = a8;  L = 1024; }
  else                 { i -= 163840; on = on16; ls = ls16; ax = a16; L = 256; }
  int e = i * 4;
  int c = e / L, l = e % L;
  int h = c >> 5;
  float ax0 = 0.f, ax1 = 0.f, ax2 = 0.f, ax3 = 0.f;
#pragma unroll
  for (int a = 0; a < 3; ++a) {
    float4 o = *(const float4*)&on[(size_t)(a * 128 + c) * L + l];
    float4 s = *(const float4*)&ls[(size_t)(a * 4 + h) * L + l];
    ax0 += o.x / s.x; ax1 += o.y / s.y; ax2 += o.z / s.z; ax3 += o.w / s.w;
  }
  const float third = 1.f / 3.f;
  float4 r = make_float4(ax0 * third, ax1 * third, ax2 * third, ax3 * third);
  *(float4*)&ax[e] = r;
}

// ---------------- fused bilinear upsample + combined 1x1 conv
__global__ __launch_bounds__(256) void fuse_kernel(
    const float* __restrict__ a16, const float* __restrict__ a8,
    const float* __restrict__ a4, const float* __restrict__ Wc,
    const float* __restrict__ bc, float* __restrict__ outp)
{
  __shared__ float Wt[32][132];
  __shared__ float Xs[32][64];
  __shared__ float patch[32][16];
  int t = threadIdx.x;
  int px0 = blockIdx.x * 8, py0 = blockIdx.y * 8;
  int og = t >> 3, pg = t & 7;
  float acc[4][8] = {};
  for (int ch = 0; ch < 12; ++ch) {
    int sci = ch >> 2;
    int coff = (ch & 3) * 32;
    int ssz; const float* src; float sf;
    if (sci == 0)      { ssz = 16; src = a16; sf = 1.f / 16.f; }
    else if (sci == 1) { ssz = 32; src = a8;  sf = 1.f / 8.f; }
    else               { ssz = 64; src = a4;  sf = 1.f / 4.f; }
    float sx0 = (px0 + 0.5f) * sf - 0.5f;
    float sy0 = (py0 + 0.5f) * sf - 0.5f;
    int x0f = (int)floorf(sx0);
    int y0f = (int)floorf(sy0);
    __syncthreads();
    { // stage Wc chunk -> Wt[k][o]
      int o = t >> 1, ki = (t & 1) * 16;
      const float* wp = Wc + o * 384 + ch * 32 + ki;
#pragma unroll
      for (int j = 0; j < 16; j += 4) {
        float4 w4 = *(const float4*)(wp + j);
        Wt[ki + j + 0][o] = w4.x; Wt[ki + j + 1][o] = w4.y;
        Wt[ki + j + 2][o] = w4.z; Wt[ki + j + 3][o] = w4.w;
      }
    }
    if (t < 128) { // stage 4x4 source patch for 32 channels
      int c = t >> 2, ry = t & 3;
      int yy = min(max(y0f + ry, 0), ssz - 1);
      const float* sp = src + (size_t)(coff + c) * ssz * ssz + yy * ssz;
#pragma unroll
      for (int rx = 0; rx < 4; ++rx) {
        int xx = min(max(x0f + rx, 0), ssz - 1);
        patch[c][ry * 4 + rx] = sp[xx];
      }
    }
    __syncthreads();
    { // bilinear -> Xs[k][p]
      int p = t & 63, cg = t >> 6;
      int px = p & 7, py = p >> 3;
      float sx = (px0 + px + 0.5f) * sf - 0.5f;
      float sy = (py0 + py + 0.5f) * sf - 0.5f;
      int xi = (int)floorf(sx), yi = (int)floorf(sy);
      float fx = sx - xi, fy = sy - yi;
      int lx = xi - x0f, ly = yi - y0f;
      int lx1 = min(xi + 1, ssz - 1) - x0f;
      int ly1 = min(yi + 1, ssz - 1) - y0f;
      float w00 = (1.f - fy) * (1.f - fx), w01 = (1.f - fy) * fx;
      float w10 = fy * (1.f - fx), w11 = fy * fx;
#pragma unroll
      for (int j = 0; j < 8; ++j) {
        int k = 8 * cg + j;
        float v = w00 * patch[k][ly * 4 + lx] + w01 * patch[k][ly * 4 + lx1]
                + w10 * patch[k][ly1 * 4 + lx] + w11 * patch[k][ly1 * 4 + lx1];
        Xs[k][p] = v;
      }
    }
    __syncthreads();
#pragma unroll 8
    for (int k = 0; k < 32; ++k) {
      float4 w4 = *(const float4*)&Wt[k][4 * og];
      float4 xa4 = *(const float4*)&Xs[k][8 * pg];
      float4 xb4 = *(const float4*)&Xs[k][8 * pg + 4];
      float wa[4] = {w4.x, w4.y, w4.z, w4.w};
      float xv[8] = {xa4.x, xa4.y, xa4.z, xa4.w, xb4.x, xb4.y, xb4.z, xb4.w};
#pragma unroll
      for (int r = 0; r < 4; ++r)
#pragma unroll
        for (int c = 0; c < 8; ++c)
          acc[r][c] = fmaf(wa[r], xv[c], acc[r][c]);
    }
  }
#pragma unroll
  for (int oi = 0; oi < 4; ++oi) {
    int o = 4 * og + oi;
    float bb = bc[o];
    float4 r0 = make_float4(acc[oi][0] + bb, acc[oi][1] + bb, acc[oi][2] + bb, acc[oi][3] + bb);
    float4 r1 = make_float4(acc[oi][4] + bb, acc[oi][5] + bb, acc[oi][6] + bb, acc[oi][7] + bb);
    float* op = outp + (size_t)o * 65536 + (py0 + pg) * 256 + px0;
    *(float4*)op = r0; *(float4*)(op + 4) = r1;
  }
}

extern "C" void kernel_launch(void* const* d_in, const int* in_sizes, int n_in,
                              void* d_out, int out_size, void* d_ws, size_t ws_size,
                              hipStream_t stream) {
  const float* query    = (const float*)d_in[0];
  const float* keys     = (const float*)d_in[1];
  const float* values   = (const float*)d_in[2];
  const float* wq       = (const float*)d_in[3];
  const float* bq       = (const float*)d_in[4];
  const float* wk       = (const float*)d_in[5];
  const float* bk       = (const float*)d_in[6];
  const float* wv       = (const float*)d_in[7];
  const float* bv       = (const float*)d_in[8];
  const float* fusion_w = (const float*)d_in[9];
  const float* fusion_b = (const float*)d_in[10];
  const float* out_w    = (const float*)d_in[11];
  const float* out_b    = (const float*)d_in[12];
  float* wsf  = (float*)d_ws;
  float* outp = (float*)d_out;

  // workspace layout (float units)
  const size_t P4   = 0;        // pooled s=4 [7][128][4096] (dead after proj)
  const size_t P8   = 3670016;  // pooled s=8
  const size_t P16  = 4587520;  // pooled s=16
  // ON/LS alias the pool region (zeroed after proj, stream-ordered):
  const size_t ON4  = 0;        // [3][128][4096] = 1572864
  const size_t LS4  = 1572864;  // [3][4][4096]   = 49152
  const size_t ON8  = 1622016;  // 393216
  const size_t LS8  = 2015232;  // 12288
  const size_t ON16 = 2027520;  // 98304
  const size_t LS16 = 2125824;  // 3072  -> end 2128896 (< P8 offset, safe)
  const size_t QB4  = 4816896;  // bf16 [4][4096][32]
  const size_t KB4  = 5079040;  // bf16 [3][4][4096][32]
  const size_t VB4  = 5865472;  // bf16 [3][4][32*4096] (frag chunks)
  const size_t QB8  = 6651904;
  const size_t KB8  = 6717440;
  const size_t VB8  = 6914048;
  const size_t QB16 = 7110656;
  const size_t KB16 = 7127040;
  const size_t VB16 = 7176192;
  const size_t A4   = 7225344;  // fp32 [128][4096]
  const size_t A8   = 7749632;
  const size_t A16  = 7880704;
  const size_t WC   = 7913472;
  const size_t BC   = 7962624;

  precomp_kernel<<<(128*384 + 128 + 255) / 256, 256, 0, stream>>>(
      fusion_w, fusion_b, out_w, out_b, wsf + WC, wsf + BC);
  pool4_kernel<<<7*128*4096/256, 256, 0, stream>>>(query, keys, values, wsf + P4);
  pool2_kernel<<<7*128*1024/256, 256, 0, stream>>>(wsf + P4, wsf + P8, 32);
  pool2_kernel<<<7*128*256/256,  256, 0, stream>>>(wsf + P8, wsf + P16, 16);

  // Q pre-scale: 1/sqrt(32) * log2(e)  (attn uses exp2 directly)
  const float qsc = 0.17677669529663687f * 1.4426950408889634f;
  proj_kernel<<<dim3(64, 2, 7), 256, 0, stream>>>(wsf + P4,
      (ushort*)(wsf + QB4), (ushort*)(wsf + KB4), (ushort*)(wsf + VB4),
      wq, bq, wk, bk, wv, bv, 2, 4096, qsc);
  proj_kernel<<<dim3(16, 2, 7), 256, 0, stream>>>(wsf + P8,
      (ushort*)(wsf + QB8), (ushort*)(wsf + KB8), (ushort*)(wsf + VB8),
      wq, bq, wk, bk, wv, bv, 1, 1024, qsc);
  proj_kernel<<<dim3(4, 2, 7), 256, 0, stream>>>(wsf + P16,
      (ushort*)(wsf + QB16), (ushort*)(wsf + KB16), (ushort*)(wsf + VB16),
      wq, bq, wk, bk, wv, bv, 0, 256, qsc);

  // zero ON/LS accumulators (pool region dead after proj; stream-ordered)
  hipMemsetAsync(wsf + ON4, 0, (size_t)2128896 * sizeof(float), stream);

  // msplit=8 for the two larger scales: 3x machine capacity in waves
  attn_mfma_kernel<<<dim3(64, 4, 24), 256, 0, stream>>>(
      (const ushort*)(wsf + QB4), (const ushort*)(wsf + KB4),
      (const ushort*)(wsf + VB4), wsf + ON4, wsf + LS4, 4096, 8);
  attn_mfma_kernel<<<dim3(16, 4, 24), 256, 0, stream>>>(
      (const ushort*)(wsf + QB8), (const ushort*)(wsf + KB8),
      (const ushort*)(wsf + VB8), wsf + ON8, wsf + LS8, 1024, 8);
  attn_mfma_kernel<<<dim3(4, 4, 12), 256, 0, stream>>>(
      (const ushort*)(wsf + QB16), (const ushort*)(wsf + KB16),
      (const ushort*)(wsf + VB16), wsf + ON16, wsf + LS16, 256, 4);

  norm_kernel<<<672, 256, 0, stream>>>(
      wsf + ON4, wsf + LS4, wsf + A4,
      wsf + ON8, wsf + LS8, wsf + A8,
      wsf + ON16, wsf + LS16, wsf + A16);

  fuse_kernel<<<dim3(32, 32), 256, 0, stream>>>(
      wsf + A16, wsf + A8, wsf + A4, wsf + WC, wsf + BC, outp);
}

// Round 2
// 517.779 us; speedup vs baseline: 1.2860x; 1.2860x over previous
//
#include <hip/hip_runtime.h>
#include <hip/hip_bf16.h>

// Problem constants: B=1, N=3, C=128, H=W=256, HEADS=4, hd=32, SCALES=[16,8,4]

typedef __attribute__((ext_vector_type(8))) short bf16x8;
typedef __attribute__((ext_vector_type(4))) float f32x4;

__device__ inline ushort rne_bf16(float x) {
  uint u = __float_as_uint(x);
  return (ushort)((u + 0x7fffu + ((u >> 16) & 1u)) >> 16);
}

__device__ inline uint pk2_bf16(float a, float b) {
  float2 f2; f2.x = a; f2.y = b;
  __hip_bfloat162 h = __float22bfloat162_rn(f2);   // v_cvt_pk_bf16_f32
  union { __hip_bfloat162 h; uint u; } cvt; cvt.h = h;
  return cvt.u;
}

// ---------------- pool by 4: query/keys/values -> pooled4 [7][128][64][64]
__global__ __launch_bounds__(256) void pool4_kernel(
    const float* __restrict__ query, const float* __restrict__ keys,
    const float* __restrict__ values, float* __restrict__ out)
{
  int idx = blockIdx.x * 256 + threadIdx.x;      // [0, 7*128*4096)
  int x = idx & 63, y = (idx >> 6) & 63, mc = idx >> 12;   // mc = map*128 + c
  int map = mc >> 7, c = mc & 127;
  const float* src;
  if (map == 0)      src = query  + (size_t)c * 65536;
  else if (map <= 3) src = keys   + (size_t)((map - 1) * 128 + c) * 65536;
  else               src = values + (size_t)((map - 4) * 128 + c) * 65536;
  src += (y * 4) * 256 + x * 4;
  float s = 0.f;
#pragma unroll
  for (int r = 0; r < 4; ++r) {
    float4 v = *(const float4*)(src + r * 256);
    s += v.x + v.y + v.z + v.w;
  }
  out[idx] = s * 0.0625f;
}

// ---------------- pool by 2 (generic): [896][2w][2w] -> [896][w][w]
__global__ __launch_bounds__(256) void pool2_kernel(
    const float* __restrict__ in, float* __restrict__ out, int hw)
{
  int idx = blockIdx.x * 256 + threadIdx.x;
  int x = idx % hw; int y = (idx / hw) % hw; int mc = idx / (hw * hw);
  int w2 = hw * 2;
  const float* s = in + (size_t)mc * w2 * w2 + (2 * y) * w2 + 2 * x;
  float2 a = *(const float2*)s;
  float2 b = *(const float2*)(s + w2);
  out[idx] = (a.x + a.y + b.x + b.y) * 0.25f;
}

// ---------------- precompute Wc = out_w @ fusion_w  [128][384], bc = out_b + out_w @ fusion_b
__global__ __launch_bounds__(256) void precomp_kernel(
    const float* __restrict__ fusion_w, const float* __restrict__ fusion_b,
    const float* __restrict__ out_w, const float* __restrict__ out_b,
    float* __restrict__ Wc, float* __restrict__ bc)
{
  int idx = blockIdx.x * 256 + threadIdx.x;
  if (idx < 128 * 384) {
    int o = idx / 384, k = idx % 384;
    float s = 0.f;
    for (int c = 0; c < 128; ++c)
      s = fmaf(out_w[o * 128 + c], fusion_w[c * 384 + k], s);
    Wc[idx] = s;
  } else if (idx < 128 * 384 + 128) {
    int o = idx - 128 * 384;
    float s = out_b[o];
    for (int c = 0; c < 128; ++c)
      s = fmaf(out_w[o * 128 + c], fusion_b[c], s);
    bc[o] = s;
  }
}

// ---------------- 1x1 conv projection -> bf16 operand arrays in MFMA layouts
// map 0: qb[head][L][32] (scaled);  maps 1-3: kb[a][head][L][32]
// maps 4-6: vb[a][head] in MFMA-frag chunks: chunk=(m>>5)*2+(d>>4), 512 elems:
//           [d&15][ (m>>3)&3 ][ m&7 ]  -> attn reads 1 KB fully coalesced
__global__ __launch_bounds__(256) void proj_kernel(
    const float* __restrict__ pooled,
    ushort* __restrict__ qb, ushort* __restrict__ kbb, ushort* __restrict__ vbb,
    const float* __restrict__ wq, const float* __restrict__ bq,
    const float* __restrict__ wk, const float* __restrict__ bk,
    const float* __restrict__ wv, const float* __restrict__ bv,
    int si, int L, float qscale)
{
  __shared__ float Wt[32][68];
  __shared__ float Xs[32][64];
  int map = blockIdx.z;
  int o0 = blockIdx.y * 64;
  int l0 = blockIdx.x * 64;
  const float* w; const float* b; float sc = 1.f;
  if (map == 0)      { w = wq + si * 16384; b = bq + si * 128; sc = qscale; }
  else if (map <= 3) { w = wk + si * 16384; b = bk + si * 128; }
  else               { w = wv + si * 16384; b = bv + si * 128; }
  const float* src = pooled + (size_t)map * 128 * L;
  int t = threadIdx.x;
  int og = t >> 4, lg = t & 15;
  float acc[4][4] = {};
  for (int c0 = 0; c0 < 128; c0 += 32) {
    __syncthreads();
    { // stage W[64 o][32 c] -> Wt[c][o]
      int o = t >> 2, ci = (t & 3) * 8;
      const float* wp = w + (o0 + o) * 128 + c0 + ci;
      float4 a = *(const float4*)wp, d = *(const float4*)(wp + 4);
      Wt[ci + 0][o] = a.x; Wt[ci + 1][o] = a.y; Wt[ci + 2][o] = a.z; Wt[ci + 3][o] = a.w;
      Wt[ci + 4][o] = d.x; Wt[ci + 5][o] = d.y; Wt[ci + 6][o] = d.z; Wt[ci + 7][o] = d.w;
    }
    { // stage X[32 c][64 l]
      int c = t >> 3, li = (t & 7) * 8;
      const float* xp = src + (size_t)(c0 + c) * L + l0 + li;
      float4 a = *(const float4*)xp, d = *(const float4*)(xp + 4);
      *(float4*)&Xs[c][li] = a; *(float4*)&Xs[c][li + 4] = d;
    }
    __syncthreads();
#pragma unroll 8
    for (int k = 0; k < 32; ++k) {
      float4 wv4 = *(const float4*)&Wt[k][4 * og];
      float4 xv4 = *(const float4*)&Xs[k][4 * lg];
      float wa[4] = {wv4.x, wv4.y, wv4.z, wv4.w};
      float xa[4] = {xv4.x, xv4.y, xv4.z, xv4.w};
#pragma unroll
      for (int r = 0; r < 4; ++r)
#pragma unroll
        for (int c = 0; c < 4; ++c)
          acc[r][c] = fmaf(wa[r], xa[c], acc[r][c]);
    }
  }
  float4 b4 = *(const float4*)&b[o0 + 4 * og];
  float ba[4] = {b4.x, b4.y, b4.z, b4.w};
  if (map < 4) {
    ushort* dst = (map == 0) ? qb : (kbb + (size_t)(map - 1) * L * 32 * 4);
    int o4 = o0 + 4 * og;
    size_t hbase = (size_t)(o4 >> 5) * L * 32 + (o4 & 31);
#pragma unroll
    for (int li = 0; li < 4; ++li) {
      ushort4 r;
      r.x = rne_bf16((acc[0][li] + ba[0]) * sc);
      r.y = rne_bf16((acc[1][li] + ba[1]) * sc);
      r.z = rne_bf16((acc[2][li] + ba[2]) * sc);
      r.w = rne_bf16((acc[3][li] + ba[3]) * sc);
      *(ushort4*)&dst[hbase + (size_t)(l0 + 4 * lg + li) * 32] = r;
    }
  } else {
    ushort* dst = vbb + (size_t)(map - 4) * 128 * L;   // per-anchor 4 heads * 32*L
    int m = l0 + 4 * lg;                               // 4-aligned
#pragma unroll
    for (int oi = 0; oi < 4; ++oi) {
      int o = o0 + 4 * og + oi;            // c = h*32 + d
      int h = o >> 5, d = o & 31;
      ushort4 r;
      r.x = rne_bf16(acc[oi][0] + ba[oi]);
      r.y = rne_bf16(acc[oi][1] + ba[oi]);
      r.z = rne_bf16(acc[oi][2] + ba[oi]);
      r.w = rne_bf16(acc[oi][3] + ba[oi]);
      size_t off = (size_t)h * 32 * L
                 + ((size_t)(m >> 5) * 2 + (d >> 4)) * 512
                 + (size_t)(d & 15) * 32 + ((m >> 3) & 3) * 8 + (m & 7);
      *(ushort4*)&dst[off] = r;
    }
  }
}

// ---------------- MFMA flash attention, S^T form, P double-buffered in LDS.
// NO atomics: each (mpart, anchor, head, l-range) owns a disjoint slice of the
// partial buffers onp[mp][a][c][L], lsp[mp][a][h][L]; norm sums over mp and a.
// Row-sums of the ROUNDED P via MFMA against all-ones B (exact: P*1.0 in f32).
// Q is pre-scaled by log2(e)/sqrt(hd) in proj -> exp2 directly.
#define PSTR 72
__global__ __launch_bounds__(256, 4) void attn_mfma_kernel(
    const ushort* __restrict__ qb, const ushort* __restrict__ kb,
    const ushort* __restrict__ vb, float* __restrict__ onp,
    float* __restrict__ lsp, int L, int msplit)
{
  __shared__ __align__(16) ushort P[2][4][16][PSTR];   // 18432 B
  int t = threadIdx.x;
  int wave = t >> 6, lane = t & 63;
  int col = lane & 15, quad = lane >> 4;
  int head = blockIdx.y;
  int anchor = blockIdx.z / msplit, mpart = blockIdx.z % msplit;
  int l = blockIdx.x * 64 + wave * 16;
  int mlen = L / msplit, mbase = mpart * mlen;
  int ntile = mlen >> 6;

  const ushort* qh = qb + (size_t)head * L * 32;
  const ushort* kh = kb + ((size_t)anchor * 4 + head) * L * 32;
  const ushort* vh = vb + ((size_t)anchor * 4 + head) * 32 * L;

  bf16x8 qf = *(const bf16x8*)(qh + (size_t)(l + col) * 32 + quad * 8);
  const ushort* kbase = kh + (size_t)mbase * 32 + col * 32 + quad * 8;
  const ushort* vbase = vh + (size_t)(mbase >> 5) * 1024 + col * 32 + quad * 8;

  f32x4 od0 = {0.f,0.f,0.f,0.f};   // O[l-local][d 0..16)
  f32x4 od1 = {0.f,0.f,0.f,0.f};   // O[l-local][d 16..32)
  f32x4 lsa = {0.f,0.f,0.f,0.f};   // row-sums of rounded P, rows l-local
  const f32x4 z = {0.f,0.f,0.f,0.f};
  const bf16x8 ones = {16256,16256,16256,16256,16256,16256,16256,16256}; // bf16 1.0

  ushort* Pa = &P[0][wave][0][0];
  ushort* Pb = &P[1][wave][0][0];

  auto expstore = [&](f32x4 a0, f32x4 a1, f32x4 a2, f32x4 a3, ushort* Pw) {
    float sv[4][4] = {{a0.x,a0.y,a0.z,a0.w},{a1.x,a1.y,a1.z,a1.w},
                      {a2.x,a2.y,a2.z,a2.w},{a3.x,a3.y,a3.z,a3.w}};
#pragma unroll
    for (int j = 0; j < 4; ++j) {
      uint u0 = pk2_bf16(__builtin_amdgcn_exp2f(sv[j][0]),
                         __builtin_amdgcn_exp2f(sv[j][1]));
      uint u1 = pk2_bf16(__builtin_amdgcn_exp2f(sv[j][2]),
                         __builtin_amdgcn_exp2f(sv[j][3]));
      uint2 dw; dw.x = u0; dw.y = u1;
      *(uint2*)&Pw[col * PSTR + 16 * j + quad * 4] = dw;
    }
  };

  // ---- prologue: scores for tile 0, prefetch K tile 1
  bf16x8 k0 = *(const bf16x8*)(kbase);
  bf16x8 k1 = *(const bf16x8*)(kbase + 512);
  bf16x8 k2 = *(const bf16x8*)(kbase + 1024);
  bf16x8 k3 = *(const bf16x8*)(kbase + 1536);
  f32x4 s0 = __builtin_amdgcn_mfma_f32_16x16x32_bf16(k0, qf, z, 0, 0, 0);
  f32x4 s1 = __builtin_amdgcn_mfma_f32_16x16x32_bf16(k1, qf, z, 0, 0, 0);
  f32x4 s2 = __builtin_amdgcn_mfma_f32_16x16x32_bf16(k2, qf, z, 0, 0, 0);
  f32x4 s3 = __builtin_amdgcn_mfma_f32_16x16x32_bf16(k3, qf, z, 0, 0, 0);
  {
    const ushort* kp1 = kbase + ((ntile > 1) ? 64 * 32 : 0);
    k0 = *(const bf16x8*)(kp1);
    k1 = *(const bf16x8*)(kp1 + 512);
    k2 = *(const bf16x8*)(kp1 + 1024);
    k3 = *(const bf16x8*)(kp1 + 1536);
  }
  expstore(s0, s1, s2, s3, Pa);

  for (int i = 1; i < ntile; ++i) {
    // K tile i+1 (dummy reload of tile 0 on last iteration)
    const ushort* kpn = kbase + ((i + 1 < ntile) ? (i + 1) * 2048 : 0);
    bf16x8 n0 = *(const bf16x8*)(kpn);
    bf16x8 n1 = *(const bf16x8*)(kpn + 512);
    bf16x8 n2 = *(const bf16x8*)(kpn + 1024);
    bf16x8 n3 = *(const bf16x8*)(kpn + 1536);
    // V tile i-1 (consumed below)
    const ushort* vpn = vbase + (i - 1) * 2048;
    bf16x8 vA = *(const bf16x8*)(vpn);            // d 0..15,  m-chunk 0
    bf16x8 vB = *(const bf16x8*)(vpn + 1024);     // d 0..15,  m-chunk 1
    bf16x8 vC = *(const bf16x8*)(vpn + 512);      // d 16..31, m-chunk 0
    bf16x8 vD = *(const bf16x8*)(vpn + 1536);     // d 16..31, m-chunk 1
    // P tile i-1 from LDS (written one iteration ago -> wait is cheap)
    bf16x8 p0 = *(const bf16x8*)(&Pa[col * PSTR + quad * 8]);
    bf16x8 p1 = *(const bf16x8*)(&Pa[col * PSTR + 32 + quad * 8]);
    // scores for tile i
    f32x4 t0 = __builtin_amdgcn_mfma_f32_16x16x32_bf16(k0, qf, z, 0, 0, 0);
    f32x4 t1 = __builtin_amdgcn_mfma_f32_16x16x32_bf16(k1, qf, z, 0, 0, 0);
    f32x4 t2 = __builtin_amdgcn_mfma_f32_16x16x32_bf16(k2, qf, z, 0, 0, 0);
    f32x4 t3 = __builtin_amdgcn_mfma_f32_16x16x32_bf16(k3, qf, z, 0, 0, 0);
    // row-sums of rounded P (exact) + PV for tile i-1
    lsa = __builtin_amdgcn_mfma_f32_16x16x32_bf16(p0, ones, lsa, 0, 0, 0);
    lsa = __builtin_amdgcn_mfma_f32_16x16x32_bf16(p1, ones, lsa, 0, 0, 0);
    od0 = __builtin_amdgcn_mfma_f32_16x16x32_bf16(p0, vA, od0, 0, 0, 0);
    od0 = __builtin_amdgcn_mfma_f32_16x16x32_bf16(p1, vB, od0, 0, 0, 0);
    od1 = __builtin_amdgcn_mfma_f32_16x16x32_bf16(p0, vC, od1, 0, 0, 0);
    od1 = __builtin_amdgcn_mfma_f32_16x16x32_bf16(p1, vD, od1, 0, 0, 0);
    // exp2 + RNE pack tile i -> other buffer
    expstore(t0, t1, t2, t3, Pb);
    k0 = n0; k1 = n1; k2 = n2; k3 = n3;
    ushort* tp = Pa; Pa = Pb; Pb = tp;
  }

  // ---- epilogue: PV + row-sum for last tile
  {
    const ushort* vpe = vbase + (ntile - 1) * 2048;
    bf16x8 vA = *(const bf16x8*)(vpe);
    bf16x8 vB = *(const bf16x8*)(vpe + 1024);
    bf16x8 vC = *(const bf16x8*)(vpe + 512);
    bf16x8 vD = *(const bf16x8*)(vpe + 1536);
    bf16x8 p0 = *(const bf16x8*)(&Pa[col * PSTR + quad * 8]);
    bf16x8 p1 = *(const bf16x8*)(&Pa[col * PSTR + 32 + quad * 8]);
    lsa = __builtin_amdgcn_mfma_f32_16x16x32_bf16(p0, ones, lsa, 0, 0, 0);
    lsa = __builtin_amdgcn_mfma_f32_16x16x32_bf16(p1, ones, lsa, 0, 0, 0);
    od0 = __builtin_amdgcn_mfma_f32_16x16x32_bf16(p0, vA, od0, 0, 0, 0);
    od0 = __builtin_amdgcn_mfma_f32_16x16x32_bf16(p1, vB, od0, 0, 0, 0);
    od1 = __builtin_amdgcn_mfma_f32_16x16x32_bf16(p0, vC, od1, 0, 0, 0);
    od1 = __builtin_amdgcn_mfma_f32_16x16x32_bf16(p1, vD, od1, 0, 0, 0);
  }

  // plain vector stores into this block's disjoint partial slice
  float* on2 = onp + ((size_t)(mpart * 3 + anchor) * 128 + (size_t)(head * 32)) * L;
  float* ls2 = lsp + ((size_t)(mpart * 3 + anchor) * 4 + head) * L;
  // lsa D-layout: row l-local = quad*4+r (all 16 cols identical copies)
  if (col == 0)
    *(f32x4*)&ls2[l + quad * 4] = lsa;
  *(f32x4*)&on2[(size_t)col * L + l + quad * 4]        = od0;
  *(f32x4*)&on2[(size_t)(16 + col) * L + l + quad * 4] = od1;
}

// ---------------- normalize: A[c][l] = (1/3) * sum_a [Sum_mp on] / [Sum_mp ls]
// partial layout: on[(mp*3+a)*128 + c][L], ls[(mp*3+a)*4 + h][L]
__global__ __launch_bounds__(256) void norm_kernel(
    const float* __restrict__ on4,  const float* __restrict__ ls4,  float* __restrict__ a4,
    const float* __restrict__ on8,  const float* __restrict__ ls8,  float* __restrict__ a8,
    const float* __restrict__ on16, const float* __restrict__ ls16, float* __restrict__ a16)
{
  int i = blockIdx.x * 256 + threadIdx.x;   // float4 index
  const float* on; const float* ls; float* ax; int L; int ms;
  if (i < 131072)      { on = on4;  ls = ls4;  ax = a4;  L = 4096; ms = 2; }
  else if (i < 163840) { i -= 131072; on = on8;  ls = ls8;  ax = a8;  L = 1024; ms = 2; }
  else                 { i -= 163840; on = on16; ls = ls16; ax = a16; L = 256; ms = 4; }
  int e = i * 4;
  int c = e / L, l = e % L;
  int h = c >> 5;
  float ax0 = 0.f, ax1 = 0.f, ax2 = 0.f, ax3 = 0.f;
  for (int a = 0; a < 3; ++a) {
    float n0 = 0.f, n1 = 0.f, n2 = 0.f, n3 = 0.f;
    float d0 = 0.f, d1 = 0.f, d2 = 0.f, d3 = 0.f;
    for (int mp = 0; mp < ms; ++mp) {
      int g = mp * 3 + a;
      float4 o = *(const float4*)&on[((size_t)g * 128 + c) * L + l];
      float4 s = *(const float4*)&ls[((size_t)g * 4 + h) * L + l];
      n0 += o.x; n1 += o.y; n2 += o.z; n3 += o.w;
      d0 += s.x; d1 += s.y; d2 += s.z; d3 += s.w;
    }
    ax0 += n0 / d0; ax1 += n1 / d1; ax2 += n2 / d2; ax3 += n3 / d3;
  }
  const float third = 1.f / 3.f;
  float4 r = make_float4(ax0 * third, ax1 * third, ax2 * third, ax3 * third);
  *(float4*)&ax[e] = r;
}

// ---------------- fused bilinear upsample + combined 1x1 conv
__global__ __launch_bounds__(256) void fuse_kernel(
    const float* __restrict__ a16, const float* __restrict__ a8,
    const float* __restrict__ a4, const float* __restrict__ Wc,
    const float* __restrict__ bc, float* __restrict__ outp)
{
  __shared__ float Wt[32][132];
  __shared__ float Xs[32][64];
  __shared__ float patch[32][16];
  int t = threadIdx.x;
  int px0 = blockIdx.x * 8, py0 = blockIdx.y * 8;
  int og = t >> 3, pg = t & 7;
  float acc[4][8] = {};
  for (int ch = 0; ch < 12; ++ch) {
    int sci = ch >> 2;
    int coff = (ch & 3) * 32;
    int ssz; const float* src; float sf;
    if (sci == 0)      { ssz = 16; src = a16; sf = 1.f / 16.f; }
    else if (sci == 1) { ssz = 32; src = a8;  sf = 1.f / 8.f; }
    else               { ssz = 64; src = a4;  sf = 1.f / 4.f; }
    float sx0 = (px0 + 0.5f) * sf - 0.5f;
    float sy0 = (py0 + 0.5f) * sf - 0.5f;
    int x0f = (int)floorf(sx0);
    int y0f = (int)floorf(sy0);
    __syncthreads();
    { // stage Wc chunk -> Wt[k][o]
      int o = t >> 1, ki = (t & 1) * 16;
      const float* wp = Wc + o * 384 + ch * 32 + ki;
#pragma unroll
      for (int j = 0; j < 16; j += 4) {
        float4 w4 = *(const float4*)(wp + j);
        Wt[ki + j + 0][o] = w4.x; Wt[ki + j + 1][o] = w4.y;
        Wt[ki + j + 2][o] = w4.z; Wt[ki + j + 3][o] = w4.w;
      }
    }
    if (t < 128) { // stage 4x4 source patch for 32 channels
      int c = t >> 2, ry = t & 3;
      int yy = min(max(y0f + ry, 0), ssz - 1);
      const float* sp = src + (size_t)(coff + c) * ssz * ssz + yy * ssz;
#pragma unroll
      for (int rx = 0; rx < 4; ++rx) {
        int xx = min(max(x0f + rx, 0), ssz - 1);
        patch[c][ry * 4 + rx] = sp[xx];
      }
    }
    __syncthreads();
    { // bilinear -> Xs[k][p]
      int p = t & 63, cg = t >> 6;
      int px = p & 7, py = p >> 3;
      float sx = (px0 + px + 0.5f) * sf - 0.5f;
      float sy = (py0 + py + 0.5f) * sf - 0.5f;
      int xi = (int)floorf(sx), yi = (int)floorf(sy);
      float fx = sx - xi, fy = sy - yi;
      int lx = xi - x0f, ly = yi - y0f;
      int lx1 = min(xi + 1, ssz - 1) - x0f;
      int ly1 = min(yi + 1, ssz - 1) - y0f;
      float w00 = (1.f - fy) * (1.f - fx), w01 = (1.f - fy) * fx;
      float w10 = fy * (1.f - fx), w11 = fy * fx;
#pragma unroll
      for (int j = 0; j < 8; ++j) {
        int k = 8 * cg + j;
        float v = w00 * patch[k][ly * 4 + lx] + w01 * patch[k][ly * 4 + lx1]
                + w10 * patch[k][ly1 * 4 + lx] + w11 * patch[k][ly1 * 4 + lx1];
        Xs[k][p] = v;
      }
    }
    __syncthreads();
#pragma unroll 8
    for (int k = 0; k < 32; ++k) {
      float4 w4 = *(const float4*)&Wt[k][4 * og];
      float4 xa4 = *(const float4*)&Xs[k][8 * pg];
      float4 xb4 = *(const float4*)&Xs[k][8 * pg + 4];
      float wa[4] = {w4.x, w4.y, w4.z, w4.w};
      float xv[8] = {xa4.x, xa4.y, xa4.z, xa4.w, xb4.x, xb4.y, xb4.z, xb4.w};
#pragma unroll
      for (int r = 0; r < 4; ++r)
#pragma unroll
        for (int c = 0; c < 8; ++c)
          acc[r][c] = fmaf(wa[r], xv[c], acc[r][c]);
    }
  }
#pragma unroll
  for (int oi = 0; oi < 4; ++oi) {
    int o = 4 * og + oi;
    float bb = bc[o];
    float4 r0 = make_float4(acc[oi][0] + bb, acc[oi][1] + bb, acc[oi][2] + bb, acc[oi][3] + bb);
    float4 r1 = make_float4(acc[oi][4] + bb, acc[oi][5] + bb, acc[oi][6] + bb, acc[oi][7] + bb);
    float* op = outp + (size_t)o * 65536 + (py0 + pg) * 256 + px0;
    *(float4*)op = r0; *(float4*)(op + 4) = r1;
  }
}

extern "C" void kernel_launch(void* const* d_in, const int* in_sizes, int n_in,
                              void* d_out, int out_size, void* d_ws, size_t ws_size,
                              hipStream_t stream) {
  const float* query    = (const float*)d_in[0];
  const float* keys     = (const float*)d_in[1];
  const float* values   = (const float*)d_in[2];
  const float* wq       = (const float*)d_in[3];
  const float* bq       = (const float*)d_in[4];
  const float* wk       = (const float*)d_in[5];
  const float* bk       = (const float*)d_in[6];
  const float* wv       = (const float*)d_in[7];
  const float* bv       = (const float*)d_in[8];
  const float* fusion_w = (const float*)d_in[9];
  const float* fusion_b = (const float*)d_in[10];
  const float* out_w    = (const float*)d_in[11];
  const float* out_b    = (const float*)d_in[12];
  float* wsf  = (float*)d_ws;
  float* outp = (float*)d_out;

  // workspace layout (float units)
  const size_t P4   = 0;        // pooled s=4 [7][128][4096] (dead after proj)
  const size_t P8   = 3670016;  // pooled s=8
  const size_t P16  = 4587520;  // pooled s=16 (pool region ends 4816896)
  // Partial accumulators alias the (dead after proj) pool region, no memset:
  const size_t ONP4  = 0;        // [2][3][128][4096] = 3145728
  const size_t LSP4  = 3145728;  // [2][3][4][4096]   = 98304
  const size_t ONP8  = 3244032;  // [2][3][128][1024] = 786432
  const size_t LSP8  = 4030464;  // [2][3][4][1024]   = 24576
  const size_t ONP16 = 4055040;  // [4][3][128][256]  = 393216
  const size_t LSP16 = 4448256;  // [4][3][4][256]    = 12288 -> end 4460544 ✓
  const size_t QB4  = 4816896;  // bf16 [4][4096][32]
  const size_t KB4  = 5079040;  // bf16 [3][4][4096][32]
  const size_t VB4  = 5865472;  // bf16 [3][4][32*4096] (frag chunks)
  const size_t QB8  = 6651904;
  const size_t KB8  = 6717440;
  const size_t VB8  = 6914048;
  const size_t QB16 = 7110656;
  const size_t KB16 = 7127040;
  const size_t VB16 = 7176192;
  const size_t A4   = 7225344;  // fp32 [128][4096]
  const size_t A8   = 7749632;
  const size_t A16  = 7880704;
  const size_t WC   = 7913472;
  const size_t BC   = 7962624;

  precomp_kernel<<<(128*384 + 128 + 255) / 256, 256, 0, stream>>>(
      fusion_w, fusion_b, out_w, out_b, wsf + WC, wsf + BC);
  pool4_kernel<<<7*128*4096/256, 256, 0, stream>>>(query, keys, values, wsf + P4);
  pool2_kernel<<<7*128*1024/256, 256, 0, stream>>>(wsf + P4, wsf + P8, 32);
  pool2_kernel<<<7*128*256/256,  256, 0, stream>>>(wsf + P8, wsf + P16, 16);

  // Q pre-scale: 1/sqrt(32) * log2(e)  (attn uses exp2 directly)
  const float qsc = 0.17677669529663687f * 1.4426950408889634f;
  proj_kernel<<<dim3(64, 2, 7), 256, 0, stream>>>(wsf + P4,
      (ushort*)(wsf + QB4), (ushort*)(wsf + KB4), (ushort*)(wsf + VB4),
      wq, bq, wk, bk, wv, bv, 2, 4096, qsc);
  proj_kernel<<<dim3(16, 2, 7), 256, 0, stream>>>(wsf + P8,
      (ushort*)(wsf + QB8), (ushort*)(wsf + KB8), (ushort*)(wsf + VB8),
      wq, bq, wk, bk, wv, bv, 1, 1024, qsc);
  proj_kernel<<<dim3(4, 2, 7), 256, 0, stream>>>(wsf + P16,
      (ushort*)(wsf + QB16), (ushort*)(wsf + KB16), (ushort*)(wsf + VB16),
      wq, bq, wk, bk, wv, bv, 0, 256, qsc);

  // attn: no atomics, partial buffers; msplit=2 (s4,s8), msplit=4 (s16)
  attn_mfma_kernel<<<dim3(64, 4, 6), 256, 0, stream>>>(
      (const ushort*)(wsf + QB4), (const ushort*)(wsf + KB4),
      (const ushort*)(wsf + VB4), wsf + ONP4, wsf + LSP4, 4096, 2);
  attn_mfma_kernel<<<dim3(16, 4, 6), 256, 0, stream>>>(
      (const ushort*)(wsf + QB8), (const ushort*)(wsf + KB8),
      (const ushort*)(wsf + VB8), wsf + ONP8, wsf + LSP8, 1024, 2);
  attn_mfma_kernel<<<dim3(4, 4, 12), 256, 0, stream>>>(
      (const ushort*)(wsf + QB16), (const ushort*)(wsf + KB16),
      (const ushort*)(wsf + VB16), wsf + ONP16, wsf + LSP16, 256, 4);

  norm_kernel<<<672, 256, 0, stream>>>(
      wsf + ONP4, wsf + LSP4, wsf + A4,
      wsf + ONP8, wsf + LSP8, wsf + A8,
      wsf + ONP16, wsf + LSP16, wsf + A16);

  fuse_kernel<<<dim3(32, 32), 256, 0, stream>>>(
      wsf + A16, wsf + A8, wsf + A4, wsf + WC, wsf + BC, outp);
}

// Round 3
// 459.239 us; speedup vs baseline: 1.4499x; 1.1275x over previous
//
#include <hip/hip_runtime.h>
#include <hip/hip_bf16.h>

// Problem constants: B=1, N=3, C=128, H=W=256, HEADS=4, hd=32, SCALES=[16,8,4]

typedef __attribute__((ext_vector_type(8))) short bf16x8;
typedef __attribute__((ext_vector_type(4))) float f32x4;

__device__ inline ushort rne_bf16(float x) {
  uint u = __float_as_uint(x);
  return (ushort)((u + 0x7fffu + ((u >> 16) & 1u)) >> 16);
}

__device__ inline uint pk2_bf16(float a, float b) {
  float2 f2; f2.x = a; f2.y = b;
  __hip_bfloat162 h = __float22bfloat162_rn(f2);   // v_cvt_pk_bf16_f32
  union { __hip_bfloat162 h; uint u; } cvt; cvt.h = h;
  return cvt.u;
}

// ---------------- pool by 4: query/keys/values -> pooled4 [7][128][64][64]
__global__ __launch_bounds__(256) void pool4_kernel(
    const float* __restrict__ query, const float* __restrict__ keys,
    const float* __restrict__ values, float* __restrict__ out)
{
  int idx = blockIdx.x * 256 + threadIdx.x;      // [0, 7*128*4096)
  int x = idx & 63, y = (idx >> 6) & 63, mc = idx >> 12;   // mc = map*128 + c
  int map = mc >> 7, c = mc & 127;
  const float* src;
  if (map == 0)      src = query  + (size_t)c * 65536;
  else if (map <= 3) src = keys   + (size_t)((map - 1) * 128 + c) * 65536;
  else               src = values + (size_t)((map - 4) * 128 + c) * 65536;
  src += (y * 4) * 256 + x * 4;
  float s = 0.f;
#pragma unroll
  for (int r = 0; r < 4; ++r) {
    float4 v = *(const float4*)(src + r * 256);
    s += v.x + v.y + v.z + v.w;
  }
  out[idx] = s * 0.0625f;
}

// ---------------- pool by 2 (generic): [896][2w][2w] -> [896][w][w]
__global__ __launch_bounds__(256) void pool2_kernel(
    const float* __restrict__ in, float* __restrict__ out, int hw)
{
  int idx = blockIdx.x * 256 + threadIdx.x;
  int x = idx % hw; int y = (idx / hw) % hw; int mc = idx / (hw * hw);
  int w2 = hw * 2;
  const float* s = in + (size_t)mc * w2 * w2 + (2 * y) * w2 + 2 * x;
  float2 a = *(const float2*)s;
  float2 b = *(const float2*)(s + w2);
  out[idx] = (a.x + a.y + b.x + b.y) * 0.25f;
}

// ---------------- precompute Wc = out_w @ fusion_w  [128][384], bc = out_b + out_w @ fusion_b
__global__ __launch_bounds__(256) void precomp_kernel(
    const float* __restrict__ fusion_w, const float* __restrict__ fusion_b,
    const float* __restrict__ out_w, const float* __restrict__ out_b,
    float* __restrict__ Wc, float* __restrict__ bc)
{
  int idx = blockIdx.x * 256 + threadIdx.x;
  if (idx < 128 * 384) {
    int o = idx / 384, k = idx % 384;
    float s = 0.f;
    for (int c = 0; c < 128; ++c)
      s = fmaf(out_w[o * 128 + c], fusion_w[c * 384 + k], s);
    Wc[idx] = s;
  } else if (idx < 128 * 384 + 128) {
    int o = idx - 128 * 384;
    float s = out_b[o];
    for (int c = 0; c < 128; ++c)
      s = fmaf(out_w[o * 128 + c], fusion_b[c], s);
    bc[o] = s;
  }
}

// ---------------- 1x1 conv projection -> bf16 operand arrays in MFMA layouts
// map 0: qb[head][L][32] (scaled);  maps 1-3: kb[a][head][L][32]
// maps 4-6: vb[a][head] in MFMA-frag chunks: chunk=(m>>5)*2+(d>>4), 512 elems:
//           [d&15][ (m>>3)&3 ][ m&7 ]  -> attn reads 1 KB fully coalesced
__global__ __launch_bounds__(256) void proj_kernel(
    const float* __restrict__ pooled,
    ushort* __restrict__ qb, ushort* __restrict__ kbb, ushort* __restrict__ vbb,
    const float* __restrict__ wq, const float* __restrict__ bq,
    const float* __restrict__ wk, const float* __restrict__ bk,
    const float* __restrict__ wv, const float* __restrict__ bv,
    int si, int L, float qscale)
{
  __shared__ float Wt[32][68];
  __shared__ float Xs[32][64];
  int map = blockIdx.z;
  int o0 = blockIdx.y * 64;
  int l0 = blockIdx.x * 64;
  const float* w; const float* b; float sc = 1.f;
  if (map == 0)      { w = wq + si * 16384; b = bq + si * 128; sc = qscale; }
  else if (map <= 3) { w = wk + si * 16384; b = bk + si * 128; }
  else               { w = wv + si * 16384; b = bv + si * 128; }
  const float* src = pooled + (size_t)map * 128 * L;
  int t = threadIdx.x;
  int og = t >> 4, lg = t & 15;
  float acc[4][4] = {};
  for (int c0 = 0; c0 < 128; c0 += 32) {
    __syncthreads();
    { // stage W[64 o][32 c] -> Wt[c][o]
      int o = t >> 2, ci = (t & 3) * 8;
      const float* wp = w + (o0 + o) * 128 + c0 + ci;
      float4 a = *(const float4*)wp, d = *(const float4*)(wp + 4);
      Wt[ci + 0][o] = a.x; Wt[ci + 1][o] = a.y; Wt[ci + 2][o] = a.z; Wt[ci + 3][o] = a.w;
      Wt[ci + 4][o] = d.x; Wt[ci + 5][o] = d.y; Wt[ci + 6][o] = d.z; Wt[ci + 7][o] = d.w;
    }
    { // stage X[32 c][64 l]
      int c = t >> 3, li = (t & 7) * 8;
      const float* xp = src + (size_t)(c0 + c) * L + l0 + li;
      float4 a = *(const float4*)xp, d = *(const float4*)(xp + 4);
      *(float4*)&Xs[c][li] = a; *(float4*)&Xs[c][li + 4] = d;
    }
    __syncthreads();
#pragma unroll 8
    for (int k = 0; k < 32; ++k) {
      float4 wv4 = *(const float4*)&Wt[k][4 * og];
      float4 xv4 = *(const float4*)&Xs[k][4 * lg];
      float wa[4] = {wv4.x, wv4.y, wv4.z, wv4.w};
      float xa[4] = {xv4.x, xv4.y, xv4.z, xv4.w};
#pragma unroll
      for (int r = 0; r < 4; ++r)
#pragma unroll
        for (int c = 0; c < 4; ++c)
          acc[r][c] = fmaf(wa[r], xa[c], acc[r][c]);
    }
  }
  float4 b4 = *(const float4*)&b[o0 + 4 * og];
  float ba[4] = {b4.x, b4.y, b4.z, b4.w};
  if (map < 4) {
    ushort* dst = (map == 0) ? qb : (kbb + (size_t)(map - 1) * L * 32 * 4);
    int o4 = o0 + 4 * og;
    size_t hbase = (size_t)(o4 >> 5) * L * 32 + (o4 & 31);
#pragma unroll
    for (int li = 0; li < 4; ++li) {
      ushort4 r;
      r.x = rne_bf16((acc[0][li] + ba[0]) * sc);
      r.y = rne_bf16((acc[1][li] + ba[1]) * sc);
      r.z = rne_bf16((acc[2][li] + ba[2]) * sc);
      r.w = rne_bf16((acc[3][li] + ba[3]) * sc);
      *(ushort4*)&dst[hbase + (size_t)(l0 + 4 * lg + li) * 32] = r;
    }
  } else {
    ushort* dst = vbb + (size_t)(map - 4) * 128 * L;   // per-anchor 4 heads * 32*L
    int m = l0 + 4 * lg;                               // 4-aligned
#pragma unroll
    for (int oi = 0; oi < 4; ++oi) {
      int o = o0 + 4 * og + oi;            // c = h*32 + d
      int h = o >> 5, d = o & 31;
      ushort4 r;
      r.x = rne_bf16(acc[oi][0] + ba[oi]);
      r.y = rne_bf16(acc[oi][1] + ba[oi]);
      r.z = rne_bf16(acc[oi][2] + ba[oi]);
      r.w = rne_bf16(acc[oi][3] + ba[oi]);
      size_t off = (size_t)h * 32 * L
                 + ((size_t)(m >> 5) * 2 + (d >> 4)) * 512
                 + (size_t)(d & 15) * 32 + ((m >> 3) & 3) * 8 + (m & 7);
      *(ushort4*)&dst[off] = r;
    }
  }
}

// ---------------- MFMA flash attention, S^T form, P double-buffered in LDS.
// NO atomics: each (mpart, anchor, head, l-range) owns a disjoint slice of the
// partial buffers onp[mp][a][c][L], lsp[mp][a][h][L]; norm sums over mp and a.
// Row-sums of the ROUNDED P via MFMA against all-ones B (exact: P*1.0 in f32).
// Q is pre-scaled by log2(e)/sqrt(hd) in proj -> exp2 directly.
#define PSTR 72
__global__ __launch_bounds__(256, 4) void attn_mfma_kernel(
    const ushort* __restrict__ qb, const ushort* __restrict__ kb,
    const ushort* __restrict__ vb, float* __restrict__ onp,
    float* __restrict__ lsp, int L, int msplit)
{
  __shared__ __align__(16) ushort P[2][4][16][PSTR];   // 18432 B
  int t = threadIdx.x;
  int wave = t >> 6, lane = t & 63;
  int col = lane & 15, quad = lane >> 4;
  int head = blockIdx.y;
  int anchor = blockIdx.z / msplit, mpart = blockIdx.z % msplit;
  int l = blockIdx.x * 64 + wave * 16;
  int mlen = L / msplit, mbase = mpart * mlen;
  int ntile = mlen >> 6;

  const ushort* qh = qb + (size_t)head * L * 32;
  const ushort* kh = kb + ((size_t)anchor * 4 + head) * L * 32;
  const ushort* vh = vb + ((size_t)anchor * 4 + head) * 32 * L;

  bf16x8 qf = *(const bf16x8*)(qh + (size_t)(l + col) * 32 + quad * 8);
  const ushort* kbase = kh + (size_t)mbase * 32 + col * 32 + quad * 8;
  const ushort* vbase = vh + (size_t)(mbase >> 5) * 1024 + col * 32 + quad * 8;

  f32x4 od0 = {0.f,0.f,0.f,0.f};   // O[l-local][d 0..16)
  f32x4 od1 = {0.f,0.f,0.f,0.f};   // O[l-local][d 16..32)
  f32x4 lsa = {0.f,0.f,0.f,0.f};   // row-sums of rounded P, rows l-local
  const f32x4 z = {0.f,0.f,0.f,0.f};
  const bf16x8 ones = {16256,16256,16256,16256,16256,16256,16256,16256}; // bf16 1.0

  ushort* Pa = &P[0][wave][0][0];
  ushort* Pb = &P[1][wave][0][0];

  auto expstore = [&](f32x4 a0, f32x4 a1, f32x4 a2, f32x4 a3, ushort* Pw) {
    float sv[4][4] = {{a0.x,a0.y,a0.z,a0.w},{a1.x,a1.y,a1.z,a1.w},
                      {a2.x,a2.y,a2.z,a2.w},{a3.x,a3.y,a3.z,a3.w}};
#pragma unroll
    for (int j = 0; j < 4; ++j) {
      uint u0 = pk2_bf16(__builtin_amdgcn_exp2f(sv[j][0]),
                         __builtin_amdgcn_exp2f(sv[j][1]));
      uint u1 = pk2_bf16(__builtin_amdgcn_exp2f(sv[j][2]),
                         __builtin_amdgcn_exp2f(sv[j][3]));
      uint2 dw; dw.x = u0; dw.y = u1;
      *(uint2*)&Pw[col * PSTR + 16 * j + quad * 4] = dw;
    }
  };

  // ---- prologue: scores for tile 0, prefetch K tile 1
  bf16x8 k0 = *(const bf16x8*)(kbase);
  bf16x8 k1 = *(const bf16x8*)(kbase + 512);
  bf16x8 k2 = *(const bf16x8*)(kbase + 1024);
  bf16x8 k3 = *(const bf16x8*)(kbase + 1536);
  f32x4 s0 = __builtin_amdgcn_mfma_f32_16x16x32_bf16(k0, qf, z, 0, 0, 0);
  f32x4 s1 = __builtin_amdgcn_mfma_f32_16x16x32_bf16(k1, qf, z, 0, 0, 0);
  f32x4 s2 = __builtin_amdgcn_mfma_f32_16x16x32_bf16(k2, qf, z, 0, 0, 0);
  f32x4 s3 = __builtin_amdgcn_mfma_f32_16x16x32_bf16(k3, qf, z, 0, 0, 0);
  {
    const ushort* kp1 = kbase + ((ntile > 1) ? 64 * 32 : 0);
    k0 = *(const bf16x8*)(kp1);
    k1 = *(const bf16x8*)(kp1 + 512);
    k2 = *(const bf16x8*)(kp1 + 1024);
    k3 = *(const bf16x8*)(kp1 + 1536);
  }
  expstore(s0, s1, s2, s3, Pa);

  for (int i = 1; i < ntile; ++i) {
    // K tile i+1 (dummy reload of tile 0 on last iteration)
    const ushort* kpn = kbase + ((i + 1 < ntile) ? (i + 1) * 2048 : 0);
    bf16x8 n0 = *(const bf16x8*)(kpn);
    bf16x8 n1 = *(const bf16x8*)(kpn + 512);
    bf16x8 n2 = *(const bf16x8*)(kpn + 1024);
    bf16x8 n3 = *(const bf16x8*)(kpn + 1536);
    // V tile i-1 (consumed below)
    const ushort* vpn = vbase + (i - 1) * 2048;
    bf16x8 vA = *(const bf16x8*)(vpn);            // d 0..15,  m-chunk 0
    bf16x8 vB = *(const bf16x8*)(vpn + 1024);     // d 0..15,  m-chunk 1
    bf16x8 vC = *(const bf16x8*)(vpn + 512);      // d 16..31, m-chunk 0
    bf16x8 vD = *(const bf16x8*)(vpn + 1536);     // d 16..31, m-chunk 1
    // P tile i-1 from LDS (written one iteration ago -> wait is cheap)
    bf16x8 p0 = *(const bf16x8*)(&Pa[col * PSTR + quad * 8]);
    bf16x8 p1 = *(const bf16x8*)(&Pa[col * PSTR + 32 + quad * 8]);
    // scores for tile i
    f32x4 t0 = __builtin_amdgcn_mfma_f32_16x16x32_bf16(k0, qf, z, 0, 0, 0);
    f32x4 t1 = __builtin_amdgcn_mfma_f32_16x16x32_bf16(k1, qf, z, 0, 0, 0);
    f32x4 t2 = __builtin_amdgcn_mfma_f32_16x16x32_bf16(k2, qf, z, 0, 0, 0);
    f32x4 t3 = __builtin_amdgcn_mfma_f32_16x16x32_bf16(k3, qf, z, 0, 0, 0);
    // row-sums of rounded P (exact) + PV for tile i-1
    lsa = __builtin_amdgcn_mfma_f32_16x16x32_bf16(p0, ones, lsa, 0, 0, 0);
    lsa = __builtin_amdgcn_mfma_f32_16x16x32_bf16(p1, ones, lsa, 0, 0, 0);
    od0 = __builtin_amdgcn_mfma_f32_16x16x32_bf16(p0, vA, od0, 0, 0, 0);
    od0 = __builtin_amdgcn_mfma_f32_16x16x32_bf16(p1, vB, od0, 0, 0, 0);
    od1 = __builtin_amdgcn_mfma_f32_16x16x32_bf16(p0, vC, od1, 0, 0, 0);
    od1 = __builtin_amdgcn_mfma_f32_16x16x32_bf16(p1, vD, od1, 0, 0, 0);
    // exp2 + RNE pack tile i -> other buffer
    expstore(t0, t1, t2, t3, Pb);
    k0 = n0; k1 = n1; k2 = n2; k3 = n3;
    ushort* tp = Pa; Pa = Pb; Pb = tp;
  }

  // ---- epilogue: PV + row-sum for last tile
  {
    const ushort* vpe = vbase + (ntile - 1) * 2048;
    bf16x8 vA = *(const bf16x8*)(vpe);
    bf16x8 vB = *(const bf16x8*)(vpe + 1024);
    bf16x8 vC = *(const bf16x8*)(vpe + 512);
    bf16x8 vD = *(const bf16x8*)(vpe + 1536);
    bf16x8 p0 = *(const bf16x8*)(&Pa[col * PSTR + quad * 8]);
    bf16x8 p1 = *(const bf16x8*)(&Pa[col * PSTR + 32 + quad * 8]);
    lsa = __builtin_amdgcn_mfma_f32_16x16x32_bf16(p0, ones, lsa, 0, 0, 0);
    lsa = __builtin_amdgcn_mfma_f32_16x16x32_bf16(p1, ones, lsa, 0, 0, 0);
    od0 = __builtin_amdgcn_mfma_f32_16x16x32_bf16(p0, vA, od0, 0, 0, 0);
    od0 = __builtin_amdgcn_mfma_f32_16x16x32_bf16(p1, vB, od0, 0, 0, 0);
    od1 = __builtin_amdgcn_mfma_f32_16x16x32_bf16(p0, vC, od1, 0, 0, 0);
    od1 = __builtin_amdgcn_mfma_f32_16x16x32_bf16(p1, vD, od1, 0, 0, 0);
  }

  // plain vector stores into this block's disjoint partial slice
  float* on2 = onp + ((size_t)(mpart * 3 + anchor) * 128 + (size_t)(head * 32)) * L;
  float* ls2 = lsp + ((size_t)(mpart * 3 + anchor) * 4 + head) * L;
  // lsa D-layout: row l-local = quad*4+r (all 16 cols identical copies)
  if (col == 0)
    *(f32x4*)&ls2[l + quad * 4] = lsa;
  *(f32x4*)&on2[(size_t)col * L + l + quad * 4]        = od0;
  *(f32x4*)&on2[(size_t)(16 + col) * L + l + quad * 4] = od1;
}

// ---------------- normalize: A[c][l] = (1/3) * sum_a [Sum_mp on] / [Sum_mp ls]
// partial layout: on[(mp*3+a)*128 + c][L], ls[(mp*3+a)*4 + h][L]
__global__ __launch_bounds__(256) void norm_kernel(
    const float* __restrict__ on4,  const float* __restrict__ ls4,  float* __restrict__ a4,
    const float* __restrict__ on8,  const float* __restrict__ ls8,  float* __restrict__ a8,
    const float* __restrict__ on16, const float* __restrict__ ls16, float* __restrict__ a16)
{
  int i = blockIdx.x * 256 + threadIdx.x;   // float4 index
  const float* on; const float* ls; float* ax; int L; int ms;
  if (i < 131072)      { on = on4;  ls = ls4;  ax = a4;  L = 4096; ms = 2; }
  else if (i < 163840) { i -= 131072; on = on8;  ls = ls8;  ax = a8;  L = 1024; ms = 2; }
  else                 { i -= 163840; on = on16; ls = ls16; ax = a16; L = 256; ms = 4; }
  int e = i * 4;
  int c = e / L, l = e % L;
  int h = c >> 5;
  float ax0 = 0.f, ax1 = 0.f, ax2 = 0.f, ax3 = 0.f;
  for (int a = 0; a < 3; ++a) {
    float n0 = 0.f, n1 = 0.f, n2 = 0.f, n3 = 0.f;
    float d0 = 0.f, d1 = 0.f, d2 = 0.f, d3 = 0.f;
    for (int mp = 0; mp < ms; ++mp) {
      int g = mp * 3 + a;
      float4 o = *(const float4*)&on[((size_t)g * 128 + c) * L + l];
      float4 s = *(const float4*)&ls[((size_t)g * 4 + h) * L + l];
      n0 += o.x; n1 += o.y; n2 += o.z; n3 += o.w;
      d0 += s.x; d1 += s.y; d2 += s.z; d3 += s.w;
    }
    ax0 += n0 / d0; ax1 += n1 / d1; ax2 += n2 / d2; ax3 += n3 / d3;
  }
  const float third = 1.f / 3.f;
  float4 r = make_float4(ax0 * third, ax1 * third, ax2 * third, ax3 * third);
  *(float4*)&ax[e] = r;
}

// ---------------- Y_s = Wc_s @ A_s at LOW resolution (conv commutes with bilinear)
// bx < 4: a16 (L=256, Wc cols 0..127); bx < 20: a8 (L=1024, cols 128..255);
// else:   a4 (L=4096, cols 256..383)
__global__ __launch_bounds__(256) void ygemm_kernel(
    const float* __restrict__ a16, const float* __restrict__ a8,
    const float* __restrict__ a4, const float* __restrict__ Wc,
    float* __restrict__ y16, float* __restrict__ y8, float* __restrict__ y4)
{
  __shared__ float Wt[32][68];
  __shared__ float Xs[32][64];
  int bx = blockIdx.x;
  int o0 = blockIdx.y * 64;
  int sci; int lt; const float* src; float* dst; int L;
  if (bx < 4)       { sci = 0; lt = bx;      src = a16; dst = y16; L = 256; }
  else if (bx < 20) { sci = 1; lt = bx - 4;  src = a8;  dst = y8;  L = 1024; }
  else              { sci = 2; lt = bx - 20; src = a4;  dst = y4;  L = 4096; }
  int l0 = lt * 64;
  int coff = sci * 128;
  int t = threadIdx.x;
  int og = t >> 4, lg = t & 15;
  float acc[4][4] = {};
  for (int c0 = 0; c0 < 128; c0 += 32) {
    __syncthreads();
    { // stage Wc[64 o][32 c] -> Wt[c][o]
      int o = t >> 2, ci = (t & 3) * 8;
      const float* wp = Wc + (o0 + o) * 384 + coff + c0 + ci;
      float4 a = *(const float4*)wp, d = *(const float4*)(wp + 4);
      Wt[ci + 0][o] = a.x; Wt[ci + 1][o] = a.y; Wt[ci + 2][o] = a.z; Wt[ci + 3][o] = a.w;
      Wt[ci + 4][o] = d.x; Wt[ci + 5][o] = d.y; Wt[ci + 6][o] = d.z; Wt[ci + 7][o] = d.w;
    }
    { // stage A[32 c][64 l]
      int c = t >> 3, li = (t & 7) * 8;
      const float* xp = src + (size_t)(c0 + c) * L + l0 + li;
      float4 a = *(const float4*)xp, d = *(const float4*)(xp + 4);
      *(float4*)&Xs[c][li] = a; *(float4*)&Xs[c][li + 4] = d;
    }
    __syncthreads();
#pragma unroll 8
    for (int k = 0; k < 32; ++k) {
      float4 wv4 = *(const float4*)&Wt[k][4 * og];
      float4 xv4 = *(const float4*)&Xs[k][4 * lg];
      float wa[4] = {wv4.x, wv4.y, wv4.z, wv4.w};
      float xa[4] = {xv4.x, xv4.y, xv4.z, xv4.w};
#pragma unroll
      for (int r = 0; r < 4; ++r)
#pragma unroll
        for (int c = 0; c < 4; ++c)
          acc[r][c] = fmaf(wa[r], xa[c], acc[r][c]);
    }
  }
#pragma unroll
  for (int r = 0; r < 4; ++r) {
    float4 v = make_float4(acc[r][0], acc[r][1], acc[r][2], acc[r][3]);
    *(float4*)&dst[(size_t)(o0 + 4 * og + r) * L + l0 + 4 * lg] = v;
  }
}

// ---------------- final: out[o][p] = bc[o] + sum_s bilinear_up(Y_s)[o][p]
__device__ inline void add_bilinear(const float* __restrict__ Yrow0,
                                    const float* __restrict__ Yrow1,
                                    int ssz, float sf, float fy,
                                    int px0, float* r)
{
#pragma unroll
  for (int j = 0; j < 4; ++j) {
    float sx = (px0 + j + 0.5f) * sf - 0.5f;
    int xi = (int)floorf(sx);
    float fx = sx - xi;
    int x0 = max(xi, 0), x1 = min(xi + 1, ssz - 1);
    float a0 = Yrow0[x0], a1 = Yrow0[x1];
    float b0 = Yrow1[x0], b1 = Yrow1[x1];
    float v0 = a0 + fx * (a1 - a0);
    float v1 = b0 + fx * (b1 - b0);
    r[j] += v0 + fy * (v1 - v0);
  }
}

__global__ __launch_bounds__(256) void upsample_kernel(
    const float* __restrict__ y16, const float* __restrict__ y8,
    const float* __restrict__ y4, const float* __restrict__ bc,
    float* __restrict__ outp)
{
  int idx = blockIdx.x * 256 + threadIdx.x;   // [0, 128*256*64)
  int x4 = idx & 63, py = (idx >> 6) & 255, o = idx >> 14;
  int px0 = x4 * 4;
  float b = bc[o];
  float r[4] = {b, b, b, b};
#pragma unroll
  for (int s = 0; s < 3; ++s) {
    const float* Y; int ssz; float sf;
    if (s == 0)      { Y = y16; ssz = 16; sf = 1.f / 16.f; }
    else if (s == 1) { Y = y8;  ssz = 32; sf = 1.f / 8.f; }
    else             { Y = y4;  ssz = 64; sf = 1.f / 4.f; }
    const float* Yo = Y + (size_t)o * ssz * ssz;
    float sy = (py + 0.5f) * sf - 0.5f;
    int yi = (int)floorf(sy);
    float fy = sy - yi;
    int yy0 = max(yi, 0), yy1 = min(yi + 1, ssz - 1);
    add_bilinear(Yo + yy0 * ssz, Yo + yy1 * ssz, ssz, sf, fy, px0, r);
  }
  float4 v = make_float4(r[0], r[1], r[2], r[3]);
  *(float4*)&outp[(size_t)o * 65536 + py * 256 + px0] = v;
}

extern "C" void kernel_launch(void* const* d_in, const int* in_sizes, int n_in,
                              void* d_out, int out_size, void* d_ws, size_t ws_size,
                              hipStream_t stream) {
  const float* query    = (const float*)d_in[0];
  const float* keys     = (const float*)d_in[1];
  const float* values   = (const float*)d_in[2];
  const float* wq       = (const float*)d_in[3];
  const float* bq       = (const float*)d_in[4];
  const float* wk       = (const float*)d_in[5];
  const float* bk       = (const float*)d_in[6];
  const float* wv       = (const float*)d_in[7];
  const float* bv       = (const float*)d_in[8];
  const float* fusion_w = (const float*)d_in[9];
  const float* fusion_b = (const float*)d_in[10];
  const float* out_w    = (const float*)d_in[11];
  const float* out_b    = (const float*)d_in[12];
  float* wsf  = (float*)d_ws;
  float* outp = (float*)d_out;

  // workspace layout (float units)
  const size_t P4   = 0;        // pooled s=4 [7][128][4096] (dead after proj)
  const size_t P8   = 3670016;  // pooled s=8
  const size_t P16  = 4587520;  // pooled s=16 (pool region ends 4816896)
  // Partial accumulators alias the (dead after proj) pool region, no memset:
  const size_t ONP4  = 0;        // [2][3][128][4096] = 3145728
  const size_t LSP4  = 3145728;  // [2][3][4][4096]   = 98304
  const size_t ONP8  = 3244032;  // [2][3][128][1024] = 786432
  const size_t LSP8  = 4030464;  // [2][3][4][1024]   = 24576
  const size_t ONP16 = 4055040;  // [4][3][128][256]  = 393216
  const size_t LSP16 = 4448256;  // [4][3][4][256]    = 12288 -> end 4460544
  // Y buffers alias the ONP region (dead after norm):
  const size_t Y4   = 0;        // [128][4096] = 524288
  const size_t Y8   = 524288;   // [128][1024] = 131072
  const size_t Y16  = 655360;   // [128][256]  = 32768  -> end 688128 (< ONP end reuse ok)
  const size_t QB4  = 4816896;  // bf16 [4][4096][32]
  const size_t KB4  = 5079040;  // bf16 [3][4][4096][32]
  const size_t VB4  = 5865472;  // bf16 [3][4][32*4096] (frag chunks)
  const size_t QB8  = 6651904;
  const size_t KB8  = 6717440;
  const size_t VB8  = 6914048;
  const size_t QB16 = 7110656;
  const size_t KB16 = 7127040;
  const size_t VB16 = 7176192;
  const size_t A4   = 7225344;  // fp32 [128][4096]
  const size_t A8   = 7749632;
  const size_t A16  = 7880704;
  const size_t WC   = 7913472;
  const size_t BC   = 7962624;

  precomp_kernel<<<(128*384 + 128 + 255) / 256, 256, 0, stream>>>(
      fusion_w, fusion_b, out_w, out_b, wsf + WC, wsf + BC);
  pool4_kernel<<<7*128*4096/256, 256, 0, stream>>>(query, keys, values, wsf + P4);
  pool2_kernel<<<7*128*1024/256, 256, 0, stream>>>(wsf + P4, wsf + P8, 32);
  pool2_kernel<<<7*128*256/256,  256, 0, stream>>>(wsf + P8, wsf + P16, 16);

  // Q pre-scale: 1/sqrt(32) * log2(e)  (attn uses exp2 directly)
  const float qsc = 0.17677669529663687f * 1.4426950408889634f;
  proj_kernel<<<dim3(64, 2, 7), 256, 0, stream>>>(wsf + P4,
      (ushort*)(wsf + QB4), (ushort*)(wsf + KB4), (ushort*)(wsf + VB4),
      wq, bq, wk, bk, wv, bv, 2, 4096, qsc);
  proj_kernel<<<dim3(16, 2, 7), 256, 0, stream>>>(wsf + P8,
      (ushort*)(wsf + QB8), (ushort*)(wsf + KB8), (ushort*)(wsf + VB8),
      wq, bq, wk, bk, wv, bv, 1, 1024, qsc);
  proj_kernel<<<dim3(4, 2, 7), 256, 0, stream>>>(wsf + P16,
      (ushort*)(wsf + QB16), (ushort*)(wsf + KB16), (ushort*)(wsf + VB16),
      wq, bq, wk, bk, wv, bv, 0, 256, qsc);

  // attn: no atomics, partial buffers; msplit=2 (s4,s8), msplit=4 (s16)
  attn_mfma_kernel<<<dim3(64, 4, 6), 256, 0, stream>>>(
      (const ushort*)(wsf + QB4), (const ushort*)(wsf + KB4),
      (const ushort*)(wsf + VB4), wsf + ONP4, wsf + LSP4, 4096, 2);
  attn_mfma_kernel<<<dim3(16, 4, 6), 256, 0, stream>>>(
      (const ushort*)(wsf + QB8), (const ushort*)(wsf + KB8),
      (const ushort*)(wsf + VB8), wsf + ONP8, wsf + LSP8, 1024, 2);
  attn_mfma_kernel<<<dim3(4, 4, 12), 256, 0, stream>>>(
      (const ushort*)(wsf + QB16), (const ushort*)(wsf + KB16),
      (const ushort*)(wsf + VB16), wsf + ONP16, wsf + LSP16, 256, 4);

  norm_kernel<<<672, 256, 0, stream>>>(
      wsf + ONP4, wsf + LSP4, wsf + A4,
      wsf + ONP8, wsf + LSP8, wsf + A8,
      wsf + ONP16, wsf + LSP16, wsf + A16);

  // conv commutes with bilinear: Y_s = Wc_s @ A_s at low res, then upsample+sum
  ygemm_kernel<<<dim3(84, 2), 256, 0, stream>>>(
      wsf + A16, wsf + A8, wsf + A4, wsf + WC,
      wsf + Y16, wsf + Y8, wsf + Y4);
  upsample_kernel<<<8192, 256, 0, stream>>>(
      wsf + Y16, wsf + Y8, wsf + Y4, wsf + BC, outp);
}

// Round 4
// 414.065 us; speedup vs baseline: 1.6081x; 1.1091x over previous
//
#include <hip/hip_runtime.h>
#include <hip/hip_bf16.h>

// Problem constants: B=1, N=3, C=128, H=W=256, HEADS=4, hd=32, SCALES=[16,8,4]

typedef __attribute__((ext_vector_type(8))) short bf16x8;
typedef __attribute__((ext_vector_type(4))) float f32x4;

__device__ inline ushort rne_bf16(float x) {
  uint u = __float_as_uint(x);
  return (ushort)((u + 0x7fffu + ((u >> 16) & 1u)) >> 16);
}

__device__ inline uint pk2_bf16(float a, float b) {
  float2 f2; f2.x = a; f2.y = b;
  __hip_bfloat162 h = __float22bfloat162_rn(f2);   // v_cvt_pk_bf16_f32
  union { __hip_bfloat162 h; uint u; } cvt; cvt.h = h;
  return cvt.u;
}

// ---------------- pool by 4: query/keys/values -> pooled4 [7][128][64][64]
__global__ __launch_bounds__(256) void pool4_kernel(
    const float* __restrict__ query, const float* __restrict__ keys,
    const float* __restrict__ values, float* __restrict__ out)
{
  int idx = blockIdx.x * 256 + threadIdx.x;      // [0, 7*128*4096)
  int x = idx & 63, y = (idx >> 6) & 63, mc = idx >> 12;   // mc = map*128 + c
  int map = mc >> 7, c = mc & 127;
  const float* src;
  if (map == 0)      src = query  + (size_t)c * 65536;
  else if (map <= 3) src = keys   + (size_t)((map - 1) * 128 + c) * 65536;
  else               src = values + (size_t)((map - 4) * 128 + c) * 65536;
  src += (y * 4) * 256 + x * 4;
  float s = 0.f;
#pragma unroll
  for (int r = 0; r < 4; ++r) {
    float4 v = *(const float4*)(src + r * 256);
    s += v.x + v.y + v.z + v.w;
  }
  out[idx] = s * 0.0625f;
}

// ---------------- pool by 2 (generic): [896][2w][2w] -> [896][w][w]
__global__ __launch_bounds__(256) void pool2_kernel(
    const float* __restrict__ in, float* __restrict__ out, int hw)
{
  int idx = blockIdx.x * 256 + threadIdx.x;
  int x = idx % hw; int y = (idx / hw) % hw; int mc = idx / (hw * hw);
  int w2 = hw * 2;
  const float* s = in + (size_t)mc * w2 * w2 + (2 * y) * w2 + 2 * x;
  float2 a = *(const float2*)s;
  float2 b = *(const float2*)(s + w2);
  out[idx] = (a.x + a.y + b.x + b.y) * 0.25f;
}

// ---------------- precompute Wc = out_w @ fusion_w  [128][384], bc = out_b + out_w @ fusion_b
__global__ __launch_bounds__(256) void precomp_kernel(
    const float* __restrict__ fusion_w, const float* __restrict__ fusion_b,
    const float* __restrict__ out_w, const float* __restrict__ out_b,
    float* __restrict__ Wc, float* __restrict__ bc)
{
  int idx = blockIdx.x * 256 + threadIdx.x;
  if (idx < 128 * 384) {
    int o = idx / 384, k = idx % 384;
    float s = 0.f;
    for (int c = 0; c < 128; ++c)
      s = fmaf(out_w[o * 128 + c], fusion_w[c * 384 + k], s);
    Wc[idx] = s;
  } else if (idx < 128 * 384 + 128) {
    int o = idx - 128 * 384;
    float s = out_b[o];
    for (int c = 0; c < 128; ++c)
      s = fmaf(out_w[o * 128 + c], fusion_b[c], s);
    bc[o] = s;
  }
}

// ---------------- 1x1 conv projection -> bf16 operand arrays in MFMA layouts
// map 0: qb[head][L][32] (scaled);  maps 1-3: kb[a][head][L][32]
// maps 4-6: vb[a][head] in MFMA-frag chunks: chunk=(m>>5)*2+(d>>4), 512 elems:
//           [d&15][ (m>>3)&3 ][ m&7 ]  -> attn reads 1 KB fully coalesced
__global__ __launch_bounds__(256) void proj_kernel(
    const float* __restrict__ pooled,
    ushort* __restrict__ qb, ushort* __restrict__ kbb, ushort* __restrict__ vbb,
    const float* __restrict__ wq, const float* __restrict__ bq,
    const float* __restrict__ wk, const float* __restrict__ bk,
    const float* __restrict__ wv, const float* __restrict__ bv,
    int si, int L, float qscale)
{
  __shared__ float Wt[32][68];
  __shared__ float Xs[32][64];
  int map = blockIdx.z;
  int o0 = blockIdx.y * 64;
  int l0 = blockIdx.x * 64;
  const float* w; const float* b; float sc = 1.f;
  if (map == 0)      { w = wq + si * 16384; b = bq + si * 128; sc = qscale; }
  else if (map <= 3) { w = wk + si * 16384; b = bk + si * 128; }
  else               { w = wv + si * 16384; b = bv + si * 128; }
  const float* src = pooled + (size_t)map * 128 * L;
  int t = threadIdx.x;
  int og = t >> 4, lg = t & 15;
  float acc[4][4] = {};
  for (int c0 = 0; c0 < 128; c0 += 32) {
    __syncthreads();
    { // stage W[64 o][32 c] -> Wt[c][o]
      int o = t >> 2, ci = (t & 3) * 8;
      const float* wp = w + (o0 + o) * 128 + c0 + ci;
      float4 a = *(const float4*)wp, d = *(const float4*)(wp + 4);
      Wt[ci + 0][o] = a.x; Wt[ci + 1][o] = a.y; Wt[ci + 2][o] = a.z; Wt[ci + 3][o] = a.w;
      Wt[ci + 4][o] = d.x; Wt[ci + 5][o] = d.y; Wt[ci + 6][o] = d.z; Wt[ci + 7][o] = d.w;
    }
    { // stage X[32 c][64 l]
      int c = t >> 3, li = (t & 7) * 8;
      const float* xp = src + (size_t)(c0 + c) * L + l0 + li;
      float4 a = *(const float4*)xp, d = *(const float4*)(xp + 4);
      *(float4*)&Xs[c][li] = a; *(float4*)&Xs[c][li + 4] = d;
    }
    __syncthreads();
#pragma unroll 8
    for (int k = 0; k < 32; ++k) {
      float4 wv4 = *(const float4*)&Wt[k][4 * og];
      float4 xv4 = *(const float4*)&Xs[k][4 * lg];
      float wa[4] = {wv4.x, wv4.y, wv4.z, wv4.w};
      float xa[4] = {xv4.x, xv4.y, xv4.z, xv4.w};
#pragma unroll
      for (int r = 0; r < 4; ++r)
#pragma unroll
        for (int c = 0; c < 4; ++c)
          acc[r][c] = fmaf(wa[r], xa[c], acc[r][c]);
    }
  }
  float4 b4 = *(const float4*)&b[o0 + 4 * og];
  float ba[4] = {b4.x, b4.y, b4.z, b4.w};
  if (map < 4) {
    ushort* dst = (map == 0) ? qb : (kbb + (size_t)(map - 1) * L * 32 * 4);
    int o4 = o0 + 4 * og;
    size_t hbase = (size_t)(o4 >> 5) * L * 32 + (o4 & 31);
#pragma unroll
    for (int li = 0; li < 4; ++li) {
      ushort4 r;
      r.x = rne_bf16((acc[0][li] + ba[0]) * sc);
      r.y = rne_bf16((acc[1][li] + ba[1]) * sc);
      r.z = rne_bf16((acc[2][li] + ba[2]) * sc);
      r.w = rne_bf16((acc[3][li] + ba[3]) * sc);
      *(ushort4*)&dst[hbase + (size_t)(l0 + 4 * lg + li) * 32] = r;
    }
  } else {
    ushort* dst = vbb + (size_t)(map - 4) * 128 * L;   // per-anchor 4 heads * 32*L
    int m = l0 + 4 * lg;                               // 4-aligned
#pragma unroll
    for (int oi = 0; oi < 4; ++oi) {
      int o = o0 + 4 * og + oi;            // c = h*32 + d
      int h = o >> 5, d = o & 31;
      ushort4 r;
      r.x = rne_bf16(acc[oi][0] + ba[oi]);
      r.y = rne_bf16(acc[oi][1] + ba[oi]);
      r.z = rne_bf16(acc[oi][2] + ba[oi]);
      r.w = rne_bf16(acc[oi][3] + ba[oi]);
      size_t off = (size_t)h * 32 * L
                 + ((size_t)(m >> 5) * 2 + (d >> 4)) * 512
                 + (size_t)(d & 15) * 32 + ((m >> 3) & 3) * 8 + (m & 7);
      *(ushort4*)&dst[off] = r;
    }
  }
}

// ---------------- MFMA flash attention, S^T form, QMUL=2 (32 l-rows/wave).
// Two Q-tiles per wave share one K/V stream: halves K/V L2 traffic and doubles
// per-wave MFMA ILP. P double-buffered in LDS per (wave, half).
// NO atomics: disjoint partial slices onp[mp][a][c][L], lsp[mp][a][h][L].
// Row-sums of ROUNDED P via MFMA vs all-ones B (exact in f32 accumulate).
// Q pre-scaled by log2(e)/sqrt(hd) -> exp2 directly.
#define PSTR 72
__global__ __launch_bounds__(256, 4) void attn_mfma_kernel(
    const ushort* __restrict__ qb, const ushort* __restrict__ kb,
    const ushort* __restrict__ vb, float* __restrict__ onp,
    float* __restrict__ lsp, int L, int msplit)
{
  __shared__ __align__(16) ushort P[2][4][2][16][PSTR];   // 36864 B
  int t = threadIdx.x;
  int wave = t >> 6, lane = t & 63;
  int col = lane & 15, quad = lane >> 4;
  int head = blockIdx.y;
  int anchor = blockIdx.z / msplit, mpart = blockIdx.z % msplit;
  int l = blockIdx.x * 128 + wave * 32;      // half A: l.., half B: l+16..
  int mlen = L / msplit, mbase = mpart * mlen;
  int ntile = mlen >> 6;

  const ushort* qh = qb + (size_t)head * L * 32;
  const ushort* kh = kb + ((size_t)anchor * 4 + head) * L * 32;
  const ushort* vh = vb + ((size_t)anchor * 4 + head) * 32 * L;

  bf16x8 qfA = *(const bf16x8*)(qh + (size_t)(l + col) * 32 + quad * 8);
  bf16x8 qfB = *(const bf16x8*)(qh + (size_t)(l + 16 + col) * 32 + quad * 8);
  const ushort* kbase = kh + (size_t)mbase * 32 + col * 32 + quad * 8;
  const ushort* vbase = vh + (size_t)(mbase >> 5) * 1024 + col * 32 + quad * 8;

  f32x4 odA0 = {0.f,0.f,0.f,0.f}, odA1 = {0.f,0.f,0.f,0.f};
  f32x4 odB0 = {0.f,0.f,0.f,0.f}, odB1 = {0.f,0.f,0.f,0.f};
  f32x4 lsaA = {0.f,0.f,0.f,0.f}, lsaB = {0.f,0.f,0.f,0.f};
  const f32x4 z = {0.f,0.f,0.f,0.f};
  const bf16x8 ones = {16256,16256,16256,16256,16256,16256,16256,16256}; // bf16 1.0

  // per-wave base; half B lives at +16*PSTR ushorts
  ushort* Pa = &P[0][wave][0][0][0];
  ushort* Pb = &P[1][wave][0][0][0];
  const int HOF = 16 * PSTR;

  auto expstore = [&](f32x4 a0, f32x4 a1, f32x4 a2, f32x4 a3, ushort* Pw) {
    float sv[4][4] = {{a0.x,a0.y,a0.z,a0.w},{a1.x,a1.y,a1.z,a1.w},
                      {a2.x,a2.y,a2.z,a2.w},{a3.x,a3.y,a3.z,a3.w}};
#pragma unroll
    for (int j = 0; j < 4; ++j) {
      uint u0 = pk2_bf16(__builtin_amdgcn_exp2f(sv[j][0]),
                         __builtin_amdgcn_exp2f(sv[j][1]));
      uint u1 = pk2_bf16(__builtin_amdgcn_exp2f(sv[j][2]),
                         __builtin_amdgcn_exp2f(sv[j][3]));
      uint2 dw; dw.x = u0; dw.y = u1;
      *(uint2*)&Pw[col * PSTR + 16 * j + quad * 4] = dw;
    }
  };

  // ---- prologue: scores for tile 0 (both halves), then prefetch K tile 1
  bf16x8 k0 = *(const bf16x8*)(kbase);
  bf16x8 k1 = *(const bf16x8*)(kbase + 512);
  bf16x8 k2 = *(const bf16x8*)(kbase + 1024);
  bf16x8 k3 = *(const bf16x8*)(kbase + 1536);
  {
    f32x4 t0 = __builtin_amdgcn_mfma_f32_16x16x32_bf16(k0, qfA, z, 0, 0, 0);
    f32x4 t1 = __builtin_amdgcn_mfma_f32_16x16x32_bf16(k1, qfA, z, 0, 0, 0);
    f32x4 t2 = __builtin_amdgcn_mfma_f32_16x16x32_bf16(k2, qfA, z, 0, 0, 0);
    f32x4 t3 = __builtin_amdgcn_mfma_f32_16x16x32_bf16(k3, qfA, z, 0, 0, 0);
    expstore(t0, t1, t2, t3, Pa);
    t0 = __builtin_amdgcn_mfma_f32_16x16x32_bf16(k0, qfB, z, 0, 0, 0);
    t1 = __builtin_amdgcn_mfma_f32_16x16x32_bf16(k1, qfB, z, 0, 0, 0);
    t2 = __builtin_amdgcn_mfma_f32_16x16x32_bf16(k2, qfB, z, 0, 0, 0);
    t3 = __builtin_amdgcn_mfma_f32_16x16x32_bf16(k3, qfB, z, 0, 0, 0);
    const ushort* kp1 = kbase + ((ntile > 1) ? 64 * 32 : 0);
    k0 = *(const bf16x8*)(kp1);
    k1 = *(const bf16x8*)(kp1 + 512);
    k2 = *(const bf16x8*)(kp1 + 1024);
    k3 = *(const bf16x8*)(kp1 + 1536);
    expstore(t0, t1, t2, t3, Pa + HOF);
  }

  for (int i = 1; i < ntile; ++i) {
    // V tile i-1 (consumed mid-iteration)
    const ushort* vpn = vbase + (i - 1) * 2048;
    bf16x8 vA = *(const bf16x8*)(vpn);            // d 0..15,  m-chunk 0
    bf16x8 vB = *(const bf16x8*)(vpn + 1024);     // d 0..15,  m-chunk 1
    bf16x8 vC = *(const bf16x8*)(vpn + 512);      // d 16..31, m-chunk 0
    bf16x8 vD = *(const bf16x8*)(vpn + 1536);     // d 16..31, m-chunk 1
    // P tile i-1 (written one iteration ago)
    bf16x8 pA0 = *(const bf16x8*)(&Pa[col * PSTR + quad * 8]);
    bf16x8 pA1 = *(const bf16x8*)(&Pa[col * PSTR + 32 + quad * 8]);
    bf16x8 pB0 = *(const bf16x8*)(&Pa[HOF + col * PSTR + quad * 8]);
    bf16x8 pB1 = *(const bf16x8*)(&Pa[HOF + col * PSTR + 32 + quad * 8]);
    // S half A for tile i (k holds tile i)
    f32x4 t0 = __builtin_amdgcn_mfma_f32_16x16x32_bf16(k0, qfA, z, 0, 0, 0);
    f32x4 t1 = __builtin_amdgcn_mfma_f32_16x16x32_bf16(k1, qfA, z, 0, 0, 0);
    f32x4 t2 = __builtin_amdgcn_mfma_f32_16x16x32_bf16(k2, qfA, z, 0, 0, 0);
    f32x4 t3 = __builtin_amdgcn_mfma_f32_16x16x32_bf16(k3, qfA, z, 0, 0, 0);
    // PV + row-sum half A (tile i-1)
    lsaA = __builtin_amdgcn_mfma_f32_16x16x32_bf16(pA0, ones, lsaA, 0, 0, 0);
    lsaA = __builtin_amdgcn_mfma_f32_16x16x32_bf16(pA1, ones, lsaA, 0, 0, 0);
    odA0 = __builtin_amdgcn_mfma_f32_16x16x32_bf16(pA0, vA, odA0, 0, 0, 0);
    odA0 = __builtin_amdgcn_mfma_f32_16x16x32_bf16(pA1, vB, odA0, 0, 0, 0);
    odA1 = __builtin_amdgcn_mfma_f32_16x16x32_bf16(pA0, vC, odA1, 0, 0, 0);
    odA1 = __builtin_amdgcn_mfma_f32_16x16x32_bf16(pA1, vD, odA1, 0, 0, 0);
    expstore(t0, t1, t2, t3, Pb);
    // S half B for tile i (last use of k this iteration)
    t0 = __builtin_amdgcn_mfma_f32_16x16x32_bf16(k0, qfB, z, 0, 0, 0);
    t1 = __builtin_amdgcn_mfma_f32_16x16x32_bf16(k1, qfB, z, 0, 0, 0);
    t2 = __builtin_amdgcn_mfma_f32_16x16x32_bf16(k2, qfB, z, 0, 0, 0);
    t3 = __builtin_amdgcn_mfma_f32_16x16x32_bf16(k3, qfB, z, 0, 0, 0);
    // K tile i+1 (issue right after last k use; dummy tile 0 on last iter)
    {
      const ushort* kpn = kbase + ((i + 1 < ntile) ? (i + 1) * 2048 : 0);
      k0 = *(const bf16x8*)(kpn);
      k1 = *(const bf16x8*)(kpn + 512);
      k2 = *(const bf16x8*)(kpn + 1024);
      k3 = *(const bf16x8*)(kpn + 1536);
    }
    // PV + row-sum half B (tile i-1)
    lsaB = __builtin_amdgcn_mfma_f32_16x16x32_bf16(pB0, ones, lsaB, 0, 0, 0);
    lsaB = __builtin_amdgcn_mfma_f32_16x16x32_bf16(pB1, ones, lsaB, 0, 0, 0);
    odB0 = __builtin_amdgcn_mfma_f32_16x16x32_bf16(pB0, vA, odB0, 0, 0, 0);
    odB0 = __builtin_amdgcn_mfma_f32_16x16x32_bf16(pB1, vB, odB0, 0, 0, 0);
    odB1 = __builtin_amdgcn_mfma_f32_16x16x32_bf16(pB0, vC, odB1, 0, 0, 0);
    odB1 = __builtin_amdgcn_mfma_f32_16x16x32_bf16(pB1, vD, odB1, 0, 0, 0);
    expstore(t0, t1, t2, t3, Pb + HOF);
    ushort* tp = Pa; Pa = Pb; Pb = tp;
  }

  // ---- epilogue: PV + row-sum for last tile (both halves)
  {
    const ushort* vpe = vbase + (ntile - 1) * 2048;
    bf16x8 vA = *(const bf16x8*)(vpe);
    bf16x8 vB = *(const bf16x8*)(vpe + 1024);
    bf16x8 vC = *(const bf16x8*)(vpe + 512);
    bf16x8 vD = *(const bf16x8*)(vpe + 1536);
    bf16x8 pA0 = *(const bf16x8*)(&Pa[col * PSTR + quad * 8]);
    bf16x8 pA1 = *(const bf16x8*)(&Pa[col * PSTR + 32 + quad * 8]);
    bf16x8 pB0 = *(const bf16x8*)(&Pa[HOF + col * PSTR + quad * 8]);
    bf16x8 pB1 = *(const bf16x8*)(&Pa[HOF + col * PSTR + 32 + quad * 8]);
    lsaA = __builtin_amdgcn_mfma_f32_16x16x32_bf16(pA0, ones, lsaA, 0, 0, 0);
    lsaA = __builtin_amdgcn_mfma_f32_16x16x32_bf16(pA1, ones, lsaA, 0, 0, 0);
    odA0 = __builtin_amdgcn_mfma_f32_16x16x32_bf16(pA0, vA, odA0, 0, 0, 0);
    odA0 = __builtin_amdgcn_mfma_f32_16x16x32_bf16(pA1, vB, odA0, 0, 0, 0);
    odA1 = __builtin_amdgcn_mfma_f32_16x16x32_bf16(pA0, vC, odA1, 0, 0, 0);
    odA1 = __builtin_amdgcn_mfma_f32_16x16x32_bf16(pA1, vD, odA1, 0, 0, 0);
    lsaB = __builtin_amdgcn_mfma_f32_16x16x32_bf16(pB0, ones, lsaB, 0, 0, 0);
    lsaB = __builtin_amdgcn_mfma_f32_16x16x32_bf16(pB1, ones, lsaB, 0, 0, 0);
    odB0 = __builtin_amdgcn_mfma_f32_16x16x32_bf16(pB0, vA, odB0, 0, 0, 0);
    odB0 = __builtin_amdgcn_mfma_f32_16x16x32_bf16(pB1, vB, odB0, 0, 0, 0);
    odB1 = __builtin_amdgcn_mfma_f32_16x16x32_bf16(pB0, vC, odB1, 0, 0, 0);
    odB1 = __builtin_amdgcn_mfma_f32_16x16x32_bf16(pB1, vD, odB1, 0, 0, 0);
  }

  // plain vector stores into this block's disjoint partial slice
  float* on2 = onp + ((size_t)(mpart * 3 + anchor) * 128 + (size_t)(head * 32)) * L;
  float* ls2 = lsp + ((size_t)(mpart * 3 + anchor) * 4 + head) * L;
  // lsa D-layout: row l-local = quad*4+r (all 16 cols identical copies)
  if (col == 0) {
    *(f32x4*)&ls2[l + quad * 4] = lsaA;
    *(f32x4*)&ls2[l + 16 + quad * 4] = lsaB;
  }
  *(f32x4*)&on2[(size_t)col * L + l + quad * 4]             = odA0;
  *(f32x4*)&on2[(size_t)(16 + col) * L + l + quad * 4]      = odA1;
  *(f32x4*)&on2[(size_t)col * L + l + 16 + quad * 4]        = odB0;
  *(f32x4*)&on2[(size_t)(16 + col) * L + l + 16 + quad * 4] = odB1;
}

// ---------------- normalize: A[c][l] = (1/3) * sum_a [Sum_mp on] / [Sum_mp ls]
// partial layout: on[(mp*3+a)*128 + c][L], ls[(mp*3+a)*4 + h][L]; ms=2 all scales
__global__ __launch_bounds__(256) void norm_kernel(
    const float* __restrict__ on4,  const float* __restrict__ ls4,  float* __restrict__ a4,
    const float* __restrict__ on8,  const float* __restrict__ ls8,  float* __restrict__ a8,
    const float* __restrict__ on16, const float* __restrict__ ls16, float* __restrict__ a16)
{
  int i = blockIdx.x * 256 + threadIdx.x;   // float4 index
  const float* on; const float* ls; float* ax; int L;
  if (i < 131072)      { on = on4;  ls = ls4;  ax = a4;  L = 4096; }
  else if (i < 163840) { i -= 131072; on = on8;  ls = ls8;  ax = a8;  L = 1024; }
  else                 { i -= 163840; on = on16; ls = ls16; ax = a16; L = 256; }
  int e = i * 4;
  int c = e / L, l = e % L;
  int h = c >> 5;
  float ax0 = 0.f, ax1 = 0.f, ax2 = 0.f, ax3 = 0.f;
  for (int a = 0; a < 3; ++a) {
    float n0 = 0.f, n1 = 0.f, n2 = 0.f, n3 = 0.f;
    float d0 = 0.f, d1 = 0.f, d2 = 0.f, d3 = 0.f;
#pragma unroll
    for (int mp = 0; mp < 2; ++mp) {
      int g = mp * 3 + a;
      float4 o = *(const float4*)&on[((size_t)g * 128 + c) * L + l];
      float4 s = *(const float4*)&ls[((size_t)g * 4 + h) * L + l];
      n0 += o.x; n1 += o.y; n2 += o.z; n3 += o.w;
      d0 += s.x; d1 += s.y; d2 += s.z; d3 += s.w;
    }
    ax0 += n0 / d0; ax1 += n1 / d1; ax2 += n2 / d2; ax3 += n3 / d3;
  }
  const float third = 1.f / 3.f;
  float4 r = make_float4(ax0 * third, ax1 * third, ax2 * third, ax3 * third);
  *(float4*)&ax[e] = r;
}

// ---------------- Y_s = Wc_s @ A_s at LOW resolution (conv commutes with bilinear)
// bx < 4: a16 (L=256, Wc cols 0..127); bx < 20: a8 (L=1024, cols 128..255);
// else:   a4 (L=4096, cols 256..383)
__global__ __launch_bounds__(256) void ygemm_kernel(
    const float* __restrict__ a16, const float* __restrict__ a8,
    const float* __restrict__ a4, const float* __restrict__ Wc,
    float* __restrict__ y16, float* __restrict__ y8, float* __restrict__ y4)
{
  __shared__ float Wt[32][68];
  __shared__ float Xs[32][64];
  int bx = blockIdx.x;
  int o0 = blockIdx.y * 64;
  int sci; int lt; const float* src; float* dst; int L;
  if (bx < 4)       { sci = 0; lt = bx;      src = a16; dst = y16; L = 256; }
  else if (bx < 20) { sci = 1; lt = bx - 4;  src = a8;  dst = y8;  L = 1024; }
  else              { sci = 2; lt = bx - 20; src = a4;  dst = y4;  L = 4096; }
  int l0 = lt * 64;
  int coff = sci * 128;
  int t = threadIdx.x;
  int og = t >> 4, lg = t & 15;
  float acc[4][4] = {};
  for (int c0 = 0; c0 < 128; c0 += 32) {
    __syncthreads();
    { // stage Wc[64 o][32 c] -> Wt[c][o]
      int o = t >> 2, ci = (t & 3) * 8;
      const float* wp = Wc + (o0 + o) * 384 + coff + c0 + ci;
      float4 a = *(const float4*)wp, d = *(const float4*)(wp + 4);
      Wt[ci + 0][o] = a.x; Wt[ci + 1][o] = a.y; Wt[ci + 2][o] = a.z; Wt[ci + 3][o] = a.w;
      Wt[ci + 4][o] = d.x; Wt[ci + 5][o] = d.y; Wt[ci + 6][o] = d.z; Wt[ci + 7][o] = d.w;
    }
    { // stage A[32 c][64 l]
      int c = t >> 3, li = (t & 7) * 8;
      const float* xp = src + (size_t)(c0 + c) * L + l0 + li;
      float4 a = *(const float4*)xp, d = *(const float4*)(xp + 4);
      *(float4*)&Xs[c][li] = a; *(float4*)&Xs[c][li + 4] = d;
    }
    __syncthreads();
#pragma unroll 8
    for (int k = 0; k < 32; ++k) {
      float4 wv4 = *(const float4*)&Wt[k][4 * og];
      float4 xv4 = *(const float4*)&Xs[k][4 * lg];
      float wa[4] = {wv4.x, wv4.y, wv4.z, wv4.w};
      float xa[4] = {xv4.x, xv4.y, xv4.z, xv4.w};
#pragma unroll
      for (int r = 0; r < 4; ++r)
#pragma unroll
        for (int c = 0; c < 4; ++c)
          acc[r][c] = fmaf(wa[r], xa[c], acc[r][c]);
    }
  }
#pragma unroll
  for (int r = 0; r < 4; ++r) {
    float4 v = make_float4(acc[r][0], acc[r][1], acc[r][2], acc[r][3]);
    *(float4*)&dst[(size_t)(o0 + 4 * og + r) * L + l0 + 4 * lg] = v;
  }
}

// ---------------- final: out[o][p] = bc[o] + sum_s bilinear_up(Y_s)[o][p]
__device__ inline void add_bilinear(const float* __restrict__ Yrow0,
                                    const float* __restrict__ Yrow1,
                                    int ssz, float sf, float fy,
                                    int px0, float* r)
{
#pragma unroll
  for (int j = 0; j < 4; ++j) {
    float sx = (px0 + j + 0.5f) * sf - 0.5f;
    int xi = (int)floorf(sx);
    float fx = sx - xi;
    int x0 = max(xi, 0), x1 = min(xi + 1, ssz - 1);
    float a0 = Yrow0[x0], a1 = Yrow0[x1];
    float b0 = Yrow1[x0], b1 = Yrow1[x1];
    float v0 = a0 + fx * (a1 - a0);
    float v1 = b0 + fx * (b1 - b0);
    r[j] += v0 + fy * (v1 - v0);
  }
}

__global__ __launch_bounds__(256) void upsample_kernel(
    const float* __restrict__ y16, const float* __restrict__ y8,
    const float* __restrict__ y4, const float* __restrict__ bc,
    float* __restrict__ outp)
{
  int idx = blockIdx.x * 256 + threadIdx.x;   // [0, 128*256*64)
  int x4 = idx & 63, py = (idx >> 6) & 255, o = idx >> 14;
  int px0 = x4 * 4;
  float b = bc[o];
  float r[4] = {b, b, b, b};
#pragma unroll
  for (int s = 0; s < 3; ++s) {
    const float* Y; int ssz; float sf;
    if (s == 0)      { Y = y16; ssz = 16; sf = 1.f / 16.f; }
    else if (s == 1) { Y = y8;  ssz = 32; sf = 1.f / 8.f; }
    else             { Y = y4;  ssz = 64; sf = 1.f / 4.f; }
    const float* Yo = Y + (size_t)o * ssz * ssz;
    float sy = (py + 0.5f) * sf - 0.5f;
    int yi = (int)floorf(sy);
    float fy = sy - yi;
    int yy0 = max(yi, 0), yy1 = min(yi + 1, ssz - 1);
    add_bilinear(Yo + yy0 * ssz, Yo + yy1 * ssz, ssz, sf, fy, px0, r);
  }
  float4 v = make_float4(r[0], r[1], r[2], r[3]);
  *(float4*)&outp[(size_t)o * 65536 + py * 256 + px0] = v;
}

extern "C" void kernel_launch(void* const* d_in, const int* in_sizes, int n_in,
                              void* d_out, int out_size, void* d_ws, size_t ws_size,
                              hipStream_t stream) {
  const float* query    = (const float*)d_in[0];
  const float* keys     = (const float*)d_in[1];
  const float* values   = (const float*)d_in[2];
  const float* wq       = (const float*)d_in[3];
  const float* bq       = (const float*)d_in[4];
  const float* wk       = (const float*)d_in[5];
  const float* bk       = (const float*)d_in[6];
  const float* wv       = (const float*)d_in[7];
  const float* bv       = (const float*)d_in[8];
  const float* fusion_w = (const float*)d_in[9];
  const float* fusion_b = (const float*)d_in[10];
  const float* out_w    = (const float*)d_in[11];
  const float* out_b    = (const float*)d_in[12];
  float* wsf  = (float*)d_ws;
  float* outp = (float*)d_out;

  // workspace layout (float units)
  const size_t P4   = 0;        // pooled s=4 [7][128][4096] (dead after proj)
  const size_t P8   = 3670016;  // pooled s=8
  const size_t P16  = 4587520;  // pooled s=16 (pool region ends 4816896)
  // Partial accumulators alias the (dead after proj) pool region, no memset:
  const size_t ONP4  = 0;        // [2][3][128][4096] = 3145728
  const size_t LSP4  = 3145728;  // [2][3][4][4096]   = 98304
  const size_t ONP8  = 3244032;  // [2][3][128][1024] = 786432
  const size_t LSP8  = 4030464;  // [2][3][4][1024]   = 24576
  const size_t ONP16 = 4055040;  // [2][3][128][256]  = 196608
  const size_t LSP16 = 4448256;  // [2][3][4][256]    = 6144 -> end 4454400
  // Y buffers alias the ONP region (dead after norm):
  const size_t Y4   = 0;        // [128][4096] = 524288
  const size_t Y8   = 524288;   // [128][1024] = 131072
  const size_t Y16  = 655360;   // [128][256]  = 32768
  const size_t QB4  = 4816896;  // bf16 [4][4096][32]
  const size_t KB4  = 5079040;  // bf16 [3][4][4096][32]
  const size_t VB4  = 5865472;  // bf16 [3][4][32*4096] (frag chunks)
  const size_t QB8  = 6651904;
  const size_t KB8  = 6717440;
  const size_t VB8  = 6914048;
  const size_t QB16 = 7110656;
  const size_t KB16 = 7127040;
  const size_t VB16 = 7176192;
  const size_t A4   = 7225344;  // fp32 [128][4096]
  const size_t A8   = 7749632;
  const size_t A16  = 7880704;
  const size_t WC   = 7913472;
  const size_t BC   = 7962624;

  precomp_kernel<<<(128*384 + 128 + 255) / 256, 256, 0, stream>>>(
      fusion_w, fusion_b, out_w, out_b, wsf + WC, wsf + BC);
  pool4_kernel<<<7*128*4096/256, 256, 0, stream>>>(query, keys, values, wsf + P4);
  pool2_kernel<<<7*128*1024/256, 256, 0, stream>>>(wsf + P4, wsf + P8, 32);
  pool2_kernel<<<7*128*256/256,  256, 0, stream>>>(wsf + P8, wsf + P16, 16);

  // Q pre-scale: 1/sqrt(32) * log2(e)  (attn uses exp2 directly)
  const float qsc = 0.17677669529663687f * 1.4426950408889634f;
  proj_kernel<<<dim3(64, 2, 7), 256, 0, stream>>>(wsf + P4,
      (ushort*)(wsf + QB4), (ushort*)(wsf + KB4), (ushort*)(wsf + VB4),
      wq, bq, wk, bk, wv, bv, 2, 4096, qsc);
  proj_kernel<<<dim3(16, 2, 7), 256, 0, stream>>>(wsf + P8,
      (ushort*)(wsf + QB8), (ushort*)(wsf + KB8), (ushort*)(wsf + VB8),
      wq, bq, wk, bk, wv, bv, 1, 1024, qsc);
  proj_kernel<<<dim3(4, 2, 7), 256, 0, stream>>>(wsf + P16,
      (ushort*)(wsf + QB16), (ushort*)(wsf + KB16), (ushort*)(wsf + VB16),
      wq, bq, wk, bk, wv, bv, 0, 256, qsc);

  // attn: QMUL=2 (128 l-rows per block), msplit=2, no atomics
  attn_mfma_kernel<<<dim3(32, 4, 6), 256, 0, stream>>>(
      (const ushort*)(wsf + QB4), (const ushort*)(wsf + KB4),
      (const ushort*)(wsf + VB4), wsf + ONP4, wsf + LSP4, 4096, 2);
  attn_mfma_kernel<<<dim3(8, 4, 6), 256, 0, stream>>>(
      (const ushort*)(wsf + QB8), (const ushort*)(wsf + KB8),
      (const ushort*)(wsf + VB8), wsf + ONP8, wsf + LSP8, 1024, 2);
  attn_mfma_kernel<<<dim3(2, 4, 6), 256, 0, stream>>>(
      (const ushort*)(wsf + QB16), (const ushort*)(wsf + KB16),
      (const ushort*)(wsf + VB16), wsf + ONP16, wsf + LSP16, 256, 2);

  norm_kernel<<<672, 256, 0, stream>>>(
      wsf + ONP4, wsf + LSP4, wsf + A4,
      wsf + ONP8, wsf + LSP8, wsf + A8,
      wsf + ONP16, wsf + LSP16, wsf + A16);

  // conv commutes with bilinear: Y_s = Wc_s @ A_s at low res, then upsample+sum
  ygemm_kernel<<<dim3(84, 2), 256, 0, stream>>>(
      wsf + A16, wsf + A8, wsf + A4, wsf + WC,
      wsf + Y16, wsf + Y8, wsf + Y4);
  upsample_kernel<<<8192, 256, 0, stream>>>(
      wsf + Y16, wsf + Y8, wsf + Y4, wsf + BC, outp);
}